// Round 1
// baseline (21339.868 us; speedup 1.0000x reference)
//
#include <hip/hip_runtime.h>
#include <hip/hip_bf16.h>

// DeepLSTM on MI355X.
// Structure:
//   k_detect  : decide if float inputs are bf16 or f32 (harness ambiguity hedge)
//   k_pack_a  : pack [W0x | W1x[:256] | W2x[:256]] into MFMA B-fragment order (col-permuted i8j8f8o8)
//   k_pack_r  : pack recurrent weights (W0h, [W1x[256:];W1h], [W2x[256:];W2h]) into B-frag order per block
//   k_gemm_x  : Ax[t][b][3072] = x_t @ Wx + b  (all timesteps of a chunk, MFMA 16x16x32 bf16)
//   k_rec     : persistent 32-block recurrence, 3 stages/step, 2 device barriers/step,
//               weights resident (stage0 in VGPRs, stages 1/2 in 64KB LDS), c-state in registers.

typedef __attribute__((ext_vector_type(8))) short short8;
typedef __attribute__((ext_vector_type(4))) float f32x4;
typedef unsigned short u16;
typedef unsigned int u32;

#define TSEQ 1000
#define NBLK 32
// ws layout (bytes)
#define O_FLAG 0L
#define O_BAR 256L
#define O_H 512L                 // h[3][2][64][256] bf16 = 196608
#define O_C 197120L              // c_save[3][64][256] f32 = 196608
#define O_BPA 393728L            // packed phase-A B: 192 tiles * 8 ks * 64 lanes * 16B = 1572864
#define O_BPR 1966592L           // packed rec B: 32 blk * 80 fb * 64 lanes * 16B = 2621440
#define O_AX 4588032L            // Ax chunk: tc*64*3072*2 bytes

__device__ __forceinline__ u16 f2b(float v) {
    __hip_bfloat16 h = __float2bfloat16(v);
    u16 u; __builtin_memcpy(&u, &h, 2); return u;
}
__device__ __forceinline__ float b2f(u16 u) {
    __hip_bfloat16 h; __builtin_memcpy(&h, &u, 2); return __bfloat162float(h);
}
__device__ __forceinline__ float rdw(const void* p, long i, int isbf) {
    return isbf ? b2f(((const u16*)p)[i]) : ((const float*)p)[i];
}
__device__ __forceinline__ float sigm(float x) { return 1.0f / (1.0f + __expf(-x)); }
__device__ __forceinline__ float tanh_(float x) { return 1.0f - 2.0f / (1.0f + __expf(2.0f * x)); }
__device__ __forceinline__ f32x4 mfma16(short8 a, short8 b, f32x4 c) {
    return __builtin_amdgcn_mfma_f32_16x16x32_bf16(a, b, c, 0, 0, 0);
}

// ---------- dtype detect: bf16 arrays have a valid small-float exponent in the LOW 16 bits ----------
__global__ void k_detect(const u32* __restrict__ embw, int* flag) {
    __shared__ int cnt[256];
    int tid = threadIdx.x, c = 0;
    for (int i = 0; i < 16; ++i) {
        u32 w = embw[tid * 16 + i];
        u32 e = (w >> 7) & 0xFF;          // exponent field of low-half bf16
        c += (e >= 110 && e <= 126) ? 1 : 0;
    }
    cnt[tid] = c; __syncthreads();
    for (int s = 128; s > 0; s >>= 1) { if (tid < s) cnt[tid] += cnt[tid + s]; __syncthreads(); }
    if (tid == 0) flag[0] = (cnt[0] > 2048) ? 1 : 0;   // bf16 ~95% hit, f32 mantissa ~7%
}

// ---------- pack phase-A B (x-part weights), col-permuted: tile t covers 16 cols ----------
// tile = L*64 + bk*2 + half ; col-in-tile n16 -> gate g = half*2 + (n16>>3), unit u = n16&7,
// original col n = g*256 + bk*8 + u
__global__ void k_pack_a(const void* W0x, const void* W1x, const void* W2x, void* wsv) {
    char* ws = (char*)wsv;
    int isbf = *(const int*)(ws + O_FLAG);
    int l = threadIdx.x & 63, w = threadIdx.x >> 6;
    int gid = blockIdx.x * 4 + w;          // 0..1535 = tile*8 + ks
    int tile = gid >> 3, ks = gid & 7;
    int L = tile >> 6, wi = tile & 63, bk = wi >> 1, half = wi & 1;
    int n16 = l & 15, g = half * 2 + (n16 >> 3), u = n16 & 7;
    int n = g * 256 + bk * 8 + u;
    const void* W = (L == 0) ? W0x : ((L == 1) ? W1x : W2x);
    union { u16 us[8]; short8 v; } tmp;
#pragma unroll
    for (int j = 0; j < 8; ++j) {
        int k = ks * 32 + (l >> 4) * 8 + j;
        tmp.us[j] = f2b(rdw(W, (long)k * 1024 + n, isbf));
    }
    ((short8*)(ws + O_BPA))[(long)(tile * 8 + ks) * 64 + l] = tmp.v;
}

// ---------- pack recurrent B. fb: s0: nt*8+ks (0..15) | s1: 16+nt*16+ks | s2: 48+nt*16+ks ----------
__global__ void k_pack_r(const void* W0h, const void* W1x, const void* W1h,
                         const void* W2x, const void* W2h, void* wsv) {
    char* ws = (char*)wsv;
    int isbf = *(const int*)(ws + O_FLAG);
    int l = threadIdx.x & 63, w = threadIdx.x >> 6;
    int gid = blockIdx.x * 4 + w;          // 0..2559 = bk*80 + fb
    int bk = gid / 80, fb = gid % 80;
    int s, nt, ks;
    if (fb < 16) { s = 0; nt = fb >> 3; ks = fb & 7; }
    else if (fb < 48) { s = 1; int f = fb - 16; nt = f >> 4; ks = f & 15; }
    else { s = 2; int f = fb - 48; nt = f >> 4; ks = f & 15; }
    int n16 = l & 15, g = nt * 2 + (n16 >> 3), u = n16 & 7;
    int n = g * 256 + bk * 8 + u;
    union { u16 us[8]; short8 v; } tmp;
#pragma unroll
    for (int j = 0; j < 8; ++j) {
        int k = ks * 32 + (l >> 4) * 8 + j;
        float v;
        if (s == 0) v = rdw(W0h, (long)k * 1024 + n, isbf);
        else if (s == 1) v = (k < 256) ? rdw(W1x, (long)(256 + k) * 1024 + n, isbf)
                                       : rdw(W1h, (long)(k - 256) * 1024 + n, isbf);
        else v = (k < 256) ? rdw(W2x, (long)(256 + k) * 1024 + n, isbf)
                           : rdw(W2h, (long)(k - 256) * 1024 + n, isbf);
        tmp.us[j] = f2b(v);
    }
    ((short8*)(ws + O_BPR))[(long)bk * 80 * 64 + (long)fb * 64 + l] = tmp.v;
}

// ---------- phase A: Ax[tl][b][P] = emb[ids[b][t]] @ Wx + bias, bf16, permuted cols ----------
__global__ __launch_bounds__(256, 1) void k_gemm_x(
    const int* __restrict__ ids, const void* __restrict__ emb,
    const void* b0, const void* b1, const void* b2, void* wsv, int t0) {
    char* ws = (char*)wsv;
    int isbf = *(const int*)(ws + O_FLAG);
    const short8* bpa = (const short8*)(ws + O_BPA);
    u16* Ax = (u16*)(ws + O_AX);
    int tid = threadIdx.x, l = tid & 63, w = tid >> 6;
    int seg = blockIdx.x, tl = blockIdx.y, t = t0 + tl;
    int n16 = l & 15, kg = l >> 4;
    short8 a[4][8];
#pragma unroll
    for (int mt = 0; mt < 4; ++mt) {
        int b = mt * 16 + n16;
        long id = ids[b * TSEQ + t];
        if (isbf) {
            const u16* ep = (const u16*)emb + id * 256;
#pragma unroll
            for (int ks = 0; ks < 8; ++ks)
                a[mt][ks] = *(const short8*)(ep + ks * 32 + kg * 8);
        } else {
            const float* ep = (const float*)emb + id * 256;
#pragma unroll
            for (int ks = 0; ks < 8; ++ks) {
                f32x4 v0 = *(const f32x4*)(ep + ks * 32 + kg * 8);
                f32x4 v1 = *(const f32x4*)(ep + ks * 32 + kg * 8 + 4);
                union { u16 us[8]; short8 v; } tmp;
#pragma unroll
                for (int j = 0; j < 4; ++j) { tmp.us[j] = f2b(v0[j]); tmp.us[4 + j] = f2b(v1[j]); }
                a[mt][ks] = tmp.v;
            }
        }
    }
#pragma unroll
    for (int nt = 0; nt < 4; ++nt) {
        int tile = seg * 16 + w * 4 + nt;
        f32x4 acc[4];
#pragma unroll
        for (int mt = 0; mt < 4; ++mt) acc[mt] = (f32x4){0.f, 0.f, 0.f, 0.f};
#pragma unroll
        for (int ks = 0; ks < 8; ++ks) {
            short8 bb = bpa[(long)(tile * 8 + ks) * 64 + l];
#pragma unroll
            for (int mt = 0; mt < 4; ++mt) acc[mt] = mfma16(a[mt][ks], bb, acc[mt]);
        }
        int L = tile >> 6, wi = tile & 63, bkk = wi >> 1, half = wi & 1;
        int g = half * 2 + (n16 >> 3), u = n16 & 7;
        const void* bias = (L == 0) ? b0 : ((L == 1) ? b1 : b2);
        float bv = rdw(bias, g * 256 + bkk * 8 + u, isbf);
        int P = tile * 16 + n16;
#pragma unroll
        for (int mt = 0; mt < 4; ++mt)
#pragma unroll
            for (int i = 0; i < 4; ++i) {
                int row = mt * 16 + kg * 4 + i;   // C-layout: row=(lane>>4)*4+i, col=lane&15
                Ax[(long)(tl * 64 + row) * 3072 + P] = f2b(acc[mt][i] + bv);
            }
    }
}

// ---------- device-scope sense barrier ----------
__device__ __forceinline__ void gbar(int* cnt, int* flag, int* lph) {
    __threadfence();
    __syncthreads();
    if (threadIdx.x == 0) {
        int p = ++(*lph);
        int prev = __hip_atomic_fetch_add(cnt, 1, __ATOMIC_ACQ_REL, __HIP_MEMORY_SCOPE_AGENT);
        if (prev == NBLK - 1) {
            __hip_atomic_store(cnt, 0, __ATOMIC_RELAXED, __HIP_MEMORY_SCOPE_AGENT);
            __hip_atomic_store(flag, p, __ATOMIC_RELEASE, __HIP_MEMORY_SCOPE_AGENT);
        } else {
            while (__hip_atomic_load(flag, __ATOMIC_ACQUIRE, __HIP_MEMORY_SCOPE_AGENT) < p) {}
        }
    }
    __syncthreads();
}

__device__ __forceinline__ void gate_update(f32x4 acc0, f32x4 acc1,
    const float* ax0, const float* ax1, float* cst, u16* hOut, int w, int l, int hu) {
    int n16 = l & 15, kg = l >> 4;
    bool own = n16 < 8;
#pragma unroll
    for (int i = 0; i < 4; ++i) {
        float g0 = acc0[i] + ax0[i];   // own: i-gate | partner: j-gate
        float g1 = acc1[i] + ax1[i];   // own: f-gate | partner: o-gate
        float pj = __shfl_xor(g0, 8, 64);
        float po = __shfl_xor(g1, 8, 64);
        float cn = sigm(g1) * cst[i] + sigm(g0) * tanh_(pj);
        float hn = sigm(po) * tanh_(cn);
        cst[i] = own ? cn : 0.0f;
        if (own) {
            int row = w * 16 + kg * 4 + i;
            hOut[row * 256 + hu] = f2b(hn);
        }
    }
}

// stage with K=256 (layer 0), B in registers
__device__ __forceinline__ void stage1mat(const short8* w0a, const short8* w0b,
    const u16* hA0, const u16* axp, int axc, float* cst, u16* hOut, int w, int l, int hu) {
    int n16 = l & 15, kg = l >> 4;
    f32x4 acc0 = {0.f, 0.f, 0.f, 0.f}, acc1 = {0.f, 0.f, 0.f, 0.f};
    float ax0[4], ax1[4];
#pragma unroll
    for (int i = 0; i < 4; ++i) {
        int row = w * 16 + kg * 4 + i;
        ax0[i] = b2f(axp[(long)row * 3072 + axc + n16]);
        ax1[i] = b2f(axp[(long)row * 3072 + axc + 16 + n16]);
    }
    int arow = (w * 16 + n16) * 256 + kg * 8;
#pragma unroll
    for (int ks = 0; ks < 8; ++ks) {
        short8 a = *(const short8*)(hA0 + arow + ks * 32);
        acc0 = mfma16(a, w0a[ks], acc0);
        acc1 = mfma16(a, w0b[ks], acc1);
    }
    gate_update(acc0, acc1, ax0, ax1, cst, hOut, w, l, hu);
}

// stage with K=512 (layers 1,2), B in LDS (fb0 = 0 for L1, 32 for L2)
__device__ __forceinline__ void stage2mat(const short8* bq, int fb0,
    const u16* hA0, const u16* hA1, const u16* axp, int axc, float* cst, u16* hOut,
    int w, int l, int hu) {
    int n16 = l & 15, kg = l >> 4;
    f32x4 acc0 = {0.f, 0.f, 0.f, 0.f}, acc1 = {0.f, 0.f, 0.f, 0.f};
    float ax0[4], ax1[4];
#pragma unroll
    for (int i = 0; i < 4; ++i) {
        int row = w * 16 + kg * 4 + i;
        ax0[i] = b2f(axp[(long)row * 3072 + axc + n16]);
        ax1[i] = b2f(axp[(long)row * 3072 + axc + 16 + n16]);
    }
    int arow = (w * 16 + n16) * 256 + kg * 8;
#pragma unroll
    for (int ks = 0; ks < 16; ++ks) {
        const u16* src = (ks < 8) ? hA0 : hA1;
        short8 a = *(const short8*)(src + arow + (ks & 7) * 32);
        acc0 = mfma16(a, bq[(fb0 + ks) * 64 + l], acc0);
        acc1 = mfma16(a, bq[(fb0 + 16 + ks) * 64 + l], acc1);
    }
    gate_update(acc0, acc1, ax0, ax1, cst, hOut, w, l, hu);
}

__global__ __launch_bounds__(256, 1) void k_rec(void* wsv, void* outv, int t0, int tc, int first) {
    __shared__ short8 bq[4096];   // stages 1,2 B-frags: 64 fb * 64 lanes = 64KB
    char* ws = (char*)wsv;
    int tid = threadIdx.x, l = tid & 63, w = tid >> 6, bk = blockIdx.x;
    int isbf = *(const int*)(ws + O_FLAG);
    const short8* bpr = (const short8*)(ws + O_BPR) + (long)bk * 80 * 64;
#pragma unroll
    for (int i = 0; i < 16; ++i) bq[i * 256 + tid] = bpr[16 * 64 + i * 256 + tid];
    short8 w0a[8], w0b[8];
#pragma unroll
    for (int ks = 0; ks < 8; ++ks) { w0a[ks] = bpr[ks * 64 + l]; w0b[ks] = bpr[(8 + ks) * 64 + l]; }
    u16* hbuf = (u16*)(ws + O_H);
    float* csave = (float*)(ws + O_C);
    const u16* Ax = (const u16*)(ws + O_AX);
    int* cnt = (int*)(ws + O_BAR);
    int* flag = cnt + 1;
    int n16 = l & 15, kg = l >> 4;
    int hu = bk * 8 + (n16 & 7);
    bool own = n16 < 8;
    float c0[4], c1[4], c2[4];
#pragma unroll
    for (int i = 0; i < 4; ++i) {
        int row = w * 16 + kg * 4 + i;
        if (first || !own) { c0[i] = 0.f; c1[i] = 0.f; c2[i] = 0.f; }
        else {
            c0[i] = csave[(0 * 64 + row) * 256 + hu];
            c1[i] = csave[(1 * 64 + row) * 256 + hu];
            c2[i] = csave[(2 * 64 + row) * 256 + hu];
        }
    }
    __syncthreads();
    int lph = 0;
    for (int tl = 0; tl < tc; ++tl) {
        int t = t0 + tl, par = t & 1, prv = par ^ 1;
        const u16* axp = Ax + (long)tl * 64 * 3072;
        u16* h0p = hbuf + (0 * 2 + prv) * 64 * 256; u16* h0c = hbuf + (0 * 2 + par) * 64 * 256;
        u16* h1p = hbuf + (1 * 2 + prv) * 64 * 256; u16* h1c = hbuf + (1 * 2 + par) * 64 * 256;
        u16* h2p = hbuf + (2 * 2 + prv) * 64 * 256; u16* h2c = hbuf + (2 * 2 + par) * 64 * 256;
        stage1mat(w0a, w0b, h0p, axp, 0 * 1024 + bk * 32, c0, h0c, w, l, hu);
        gbar(cnt, flag, &lph);
        stage2mat(bq, 0, h0c, h1p, axp, 1 * 1024 + bk * 32, c1, h1c, w, l, hu);
        gbar(cnt, flag, &lph);
        stage2mat(bq, 32, h1c, h2p, axp, 2 * 1024 + bk * 32, c2, h2c, w, l, hu);
        // no barrier: S2(t)/S0(t+1) hazards are covered by the next step's two barriers
    }
    if (own) {
        int fpar = (t0 + tc - 1) & 1;
#pragma unroll
        for (int i = 0; i < 4; ++i) {
            int row = w * 16 + kg * 4 + i;
            csave[(0 * 64 + row) * 256 + hu] = c0[i];
            csave[(1 * 64 + row) * 256 + hu] = c1[i];
            csave[(2 * 64 + row) * 256 + hu] = c2[i];
            float h0v = b2f(hbuf[(0 * 2 + fpar) * 64 * 256 + row * 256 + hu]);
            float h1v = b2f(hbuf[(1 * 2 + fpar) * 64 * 256 + row * 256 + hu]);
            float h2v = b2f(hbuf[(2 * 2 + fpar) * 64 * 256 + row * 256 + hu]);
            if (isbf) {
                u16* o = (u16*)outv;
                o[row * 1536 + 0 + hu] = f2b(c0[i]);
                o[row * 1536 + 256 + hu] = f2b(h0v);
                o[row * 1536 + 512 + hu] = f2b(c1[i]);
                o[row * 1536 + 768 + hu] = f2b(h1v);
                o[row * 1536 + 1024 + hu] = f2b(c2[i]);
                o[row * 1536 + 1280 + hu] = f2b(h2v);
            } else {
                float* o = (float*)outv;
                o[row * 1536 + 0 + hu] = c0[i];
                o[row * 1536 + 256 + hu] = h0v;
                o[row * 1536 + 512 + hu] = c1[i];
                o[row * 1536 + 768 + hu] = h1v;
                o[row * 1536 + 1024 + hu] = c2[i];
                o[row * 1536 + 1280 + hu] = h2v;
            }
        }
    }
}

extern "C" void kernel_launch(void* const* d_in, const int* in_sizes, int n_in,
                              void* d_out, int out_size, void* d_ws, size_t ws_size,
                              hipStream_t stream) {
    const int* ids = (const int*)d_in[0];
    const void* emb = d_in[1];
    const void* W0x = d_in[2]; const void* W0h = d_in[3]; const void* b0 = d_in[4];
    const void* W1x = d_in[5]; const void* W1h = d_in[6]; const void* b1 = d_in[7];
    const void* W2x = d_in[8]; const void* W2h = d_in[9]; const void* b2 = d_in[10];
    char* ws = (char*)d_ws;

    long avail = (long)ws_size - O_AX;
    long per_t = 64L * 3072 * 2;
    int tc_max = (int)(avail / per_t);
    if (tc_max > TSEQ) tc_max = TSEQ;
    if (tc_max < 1) tc_max = 1;

    hipMemsetAsync(ws + O_H, 0, 196608, stream);
    k_detect<<<1, 256, 0, stream>>>((const u32*)emb, (int*)(ws + O_FLAG));
    k_pack_a<<<384, 256, 0, stream>>>(W0x, W1x, W2x, d_ws);
    k_pack_r<<<640, 256, 0, stream>>>(W0h, W1x, W1h, W2x, W2h, d_ws);

    int t0 = 0, first = 1;
    while (t0 < TSEQ) {
        int tc = TSEQ - t0; if (tc > tc_max) tc = tc_max;
        dim3 g(12, (unsigned)tc);
        k_gemm_x<<<g, 256, 0, stream>>>(ids, emb, b0, b1, b2, d_ws, t0);
        hipMemsetAsync(ws + O_BAR, 0, 256, stream);
        k_rec<<<NBLK, 256, 0, stream>>>(d_ws, d_out, t0, tc, first);
        first = 0;
        t0 += tc;
    }
}

// Round 2
// 11638.423 us; speedup vs baseline: 1.8336x; 1.8336x over previous
//
#include <hip/hip_runtime.h>
#include <hip/hip_bf16.h>

// DeepLSTM on MI355X — R2: single-XCD worker election + L1-only fences.
//   k_detect  : decide if float inputs are bf16 or f32
//   k_pack_a  : pack x-part weights into MFMA B-frag order (col-permuted i8j8f8o8)
//   k_pack_r  : pack recurrent weights into B-frag order per worker rank
//   k_gemm_x  : Ax chunk 0 (standalone); later chunks computed by helper blocks inside k_rec
//   k_rec     : 256-block launch; census elects 32 same-XCD workers (pigeonhole: 8*31<256
//               guarantees a winner XCD). Workers: persistent recurrence, weights resident
//               (stage0 regs, stages1/2 in 64KB LDS), 2 intra-XCD barriers/step with
//               vmcnt-release + buffer_inv-acquire (NO agent-scope bulk L2 flushes).
//               Helpers (224): compute next chunk's Ax at low priority (overlap).

typedef __attribute__((ext_vector_type(8))) short short8;
typedef __attribute__((ext_vector_type(4))) float f32x4;
typedef unsigned short u16;
typedef unsigned int u32;

#define TSEQ 1000
#define NBLK 32
#define GRID_REC 256
#define NHELP (GRID_REC - NBLK)

// ws layout (bytes)
#define O_FLAG 0L
#define O_SYNC 512L      // 256 chunk slots * 64B = 16384
#define O_H    17408L    // h[3][2][64][256] bf16 = 196608
#define O_C    214016L   // c_save[3][64][256] f32 = 196608
#define O_BPA  410624L   // packed phase-A B: 192 tiles * 8 ks * 64 lanes * 16B = 1572864
#define O_BPR  1983488L  // packed rec B: 32 rank * 80 fb * 64 lanes * 16B = 2621440
#define O_AX   4604928L  // 2 buffers of tc_max*64*3072 bf16

__device__ __forceinline__ u16 f2b(float v) {
    __hip_bfloat16 h = __float2bfloat16(v);
    u16 u; __builtin_memcpy(&u, &h, 2); return u;
}
__device__ __forceinline__ float b2f(u16 u) {
    __hip_bfloat16 h; __builtin_memcpy(&h, &u, 2); return __bfloat162float(h);
}
__device__ __forceinline__ float rdw(const void* p, long i, int isbf) {
    return isbf ? b2f(((const u16*)p)[i]) : ((const float*)p)[i];
}
__device__ __forceinline__ float sigm(float x) { return 1.0f / (1.0f + __expf(-x)); }
__device__ __forceinline__ float tanh_(float x) { return 1.0f - 2.0f / (1.0f + __expf(2.0f * x)); }
__device__ __forceinline__ f32x4 mfma16(short8 a, short8 b, f32x4 c) {
    return __builtin_amdgcn_mfma_f32_16x16x32_bf16(a, b, c, 0, 0, 0);
}

// Same-XCD memory fences: release = drain stores to L2 (XCD coherence point);
// acquire = invalidate per-CU vector L1 only. No buffer_wbl2 / sc1 bulk ops.
__device__ __forceinline__ void rel_fence() {
    asm volatile("s_waitcnt vmcnt(0) lgkmcnt(0)" ::: "memory");
}
__device__ __forceinline__ void acq_fence() {
    asm volatile("buffer_inv\ns_waitcnt vmcnt(0)" ::: "memory");
}

// ---------- dtype detect ----------
__global__ void k_detect(const u32* __restrict__ embw, int* flag) {
    __shared__ int cnt[256];
    int tid = threadIdx.x, c = 0;
    for (int i = 0; i < 16; ++i) {
        u32 w = embw[tid * 16 + i];
        u32 e = (w >> 7) & 0xFF;
        c += (e >= 110 && e <= 126) ? 1 : 0;
    }
    cnt[tid] = c; __syncthreads();
    for (int s = 128; s > 0; s >>= 1) { if (tid < s) cnt[tid] += cnt[tid + s]; __syncthreads(); }
    if (tid == 0) flag[0] = (cnt[0] > 2048) ? 1 : 0;
}

// ---------- pack phase-A B ----------
__global__ void k_pack_a(const void* W0x, const void* W1x, const void* W2x, void* wsv) {
    char* ws = (char*)wsv;
    int isbf = *(const int*)(ws + O_FLAG);
    int l = threadIdx.x & 63, w = threadIdx.x >> 6;
    int gid = blockIdx.x * 4 + w;          // 0..1535 = tile*8 + ks
    int tile = gid >> 3, ks = gid & 7;
    int L = tile >> 6, wi = tile & 63, bk = wi >> 1, half = wi & 1;
    int n16 = l & 15, g = half * 2 + (n16 >> 3), u = n16 & 7;
    int n = g * 256 + bk * 8 + u;
    const void* W = (L == 0) ? W0x : ((L == 1) ? W1x : W2x);
    union { u16 us[8]; short8 v; } tmp;
#pragma unroll
    for (int j = 0; j < 8; ++j) {
        int k = ks * 32 + (l >> 4) * 8 + j;
        tmp.us[j] = f2b(rdw(W, (long)k * 1024 + n, isbf));
    }
    ((short8*)(ws + O_BPA))[(long)(tile * 8 + ks) * 64 + l] = tmp.v;
}

// ---------- pack recurrent B ----------
__global__ void k_pack_r(const void* W0h, const void* W1x, const void* W1h,
                         const void* W2x, const void* W2h, void* wsv) {
    char* ws = (char*)wsv;
    int isbf = *(const int*)(ws + O_FLAG);
    int l = threadIdx.x & 63, w = threadIdx.x >> 6;
    int gid = blockIdx.x * 4 + w;          // 0..2559 = rank*80 + fb
    int bk = gid / 80, fb = gid % 80;
    int s, nt, ks;
    if (fb < 16) { s = 0; nt = fb >> 3; ks = fb & 7; }
    else if (fb < 48) { s = 1; int f = fb - 16; nt = f >> 4; ks = f & 15; }
    else { s = 2; int f = fb - 48; nt = f >> 4; ks = f & 15; }
    int n16 = l & 15, g = nt * 2 + (n16 >> 3), u = n16 & 7;
    int n = g * 256 + bk * 8 + u;
    union { u16 us[8]; short8 v; } tmp;
#pragma unroll
    for (int j = 0; j < 8; ++j) {
        int k = ks * 32 + (l >> 4) * 8 + j;
        float v;
        if (s == 0) v = rdw(W0h, (long)k * 1024 + n, isbf);
        else if (s == 1) v = (k < 256) ? rdw(W1x, (long)(256 + k) * 1024 + n, isbf)
                                       : rdw(W1h, (long)(k - 256) * 1024 + n, isbf);
        else v = (k < 256) ? rdw(W2x, (long)(256 + k) * 1024 + n, isbf)
                           : rdw(W2h, (long)(k - 256) * 1024 + n, isbf);
        tmp.us[j] = f2b(v);
    }
    ((short8*)(ws + O_BPR))[(long)bk * 80 * 64 + (long)fb * 64 + l] = tmp.v;
}

// ---------- one x-GEMM tile job: 64 batch rows x 256 gate cols at timestep t ----------
__device__ __forceinline__ void gemm_tile(const int* __restrict__ ids, const void* __restrict__ emb,
    const void* b0, const void* b1, const void* b2, const short8* __restrict__ bpa,
    int isbf, int seg, int t, u16* __restrict__ axp) {
    int tid = threadIdx.x, l = tid & 63, w = tid >> 6;
    int n16 = l & 15, kg = l >> 4;
    short8 a[4][8];
#pragma unroll
    for (int mt = 0; mt < 4; ++mt) {
        int b = mt * 16 + n16;
        long id = ids[b * TSEQ + t];
        if (isbf) {
            const u16* ep = (const u16*)emb + id * 256;
#pragma unroll
            for (int ks = 0; ks < 8; ++ks)
                a[mt][ks] = *(const short8*)(ep + ks * 32 + kg * 8);
        } else {
            const float* ep = (const float*)emb + id * 256;
#pragma unroll
            for (int ks = 0; ks < 8; ++ks) {
                f32x4 v0 = *(const f32x4*)(ep + ks * 32 + kg * 8);
                f32x4 v1 = *(const f32x4*)(ep + ks * 32 + kg * 8 + 4);
                union { u16 us[8]; short8 v; } tmp;
#pragma unroll
                for (int j = 0; j < 4; ++j) { tmp.us[j] = f2b(v0[j]); tmp.us[4 + j] = f2b(v1[j]); }
                a[mt][ks] = tmp.v;
            }
        }
    }
#pragma unroll
    for (int nt = 0; nt < 4; ++nt) {
        int tile = seg * 16 + w * 4 + nt;
        f32x4 acc[4];
#pragma unroll
        for (int mt = 0; mt < 4; ++mt) acc[mt] = (f32x4){0.f, 0.f, 0.f, 0.f};
#pragma unroll
        for (int ks = 0; ks < 8; ++ks) {
            short8 bb = bpa[(long)(tile * 8 + ks) * 64 + l];
#pragma unroll
            for (int mt = 0; mt < 4; ++mt) acc[mt] = mfma16(a[mt][ks], bb, acc[mt]);
        }
        int L = tile >> 6, wi = tile & 63, bkk = wi >> 1, half = wi & 1;
        int g = half * 2 + (n16 >> 3), u = n16 & 7;
        const void* bias = (L == 0) ? b0 : ((L == 1) ? b1 : b2);
        float bv = rdw(bias, g * 256 + bkk * 8 + u, isbf);
        int P = tile * 16 + n16;
#pragma unroll
        for (int mt = 0; mt < 4; ++mt)
#pragma unroll
            for (int i = 0; i < 4; ++i) {
                int row = mt * 16 + kg * 4 + i;
                axp[(long)row * 3072 + P] = f2b(acc[mt][i] + bv);
            }
    }
}

__global__ __launch_bounds__(256, 1) void k_gemm_x(
    const int* __restrict__ ids, const void* __restrict__ emb,
    const void* b0, const void* b1, const void* b2, void* wsv, int t0) {
    char* ws = (char*)wsv;
    int isbf = *(const int*)(ws + O_FLAG);
    const short8* bpa = (const short8*)(ws + O_BPA);
    u16* ax = (u16*)(ws + O_AX);   // buffer 0
    gemm_tile(ids, emb, b0, b1, b2, bpa, isbf, blockIdx.x, t0 + blockIdx.y,
              ax + (long)blockIdx.y * 196608);
}

// ---------- intra-XCD barrier over NBLK workers: monotonic counter, relaxed flag ----------
__device__ __forceinline__ void gbar32(int* syn, int* lph) {
    rel_fence();
    __syncthreads();
    if (threadIdx.x == 0) {
        int p = ++(*lph);
        int v = __hip_atomic_fetch_add(syn, 1, __ATOMIC_RELAXED, __HIP_MEMORY_SCOPE_AGENT) + 1;
        if (v == NBLK * p) {
            __hip_atomic_store(syn + 1, p, __ATOMIC_RELAXED, __HIP_MEMORY_SCOPE_AGENT);
        } else {
            while (__hip_atomic_load(syn + 1, __ATOMIC_RELAXED, __HIP_MEMORY_SCOPE_AGENT) < p)
                __builtin_amdgcn_s_sleep(1);
        }
    }
    __syncthreads();
    acq_fence();
}

__device__ __forceinline__ void gate_update(f32x4 acc0, f32x4 acc1,
    const float* ax0, const float* ax1, float* cst, u16* hOut, int w, int l, int hu) {
    int n16 = l & 15, kg = l >> 4;
    bool own = n16 < 8;
#pragma unroll
    for (int i = 0; i < 4; ++i) {
        float g0 = acc0[i] + ax0[i];   // own: i-gate | partner: j-gate
        float g1 = acc1[i] + ax1[i];   // own: f-gate | partner: o-gate
        float pj = __shfl_xor(g0, 8, 64);
        float po = __shfl_xor(g1, 8, 64);
        float cn = sigm(g1) * cst[i] + sigm(g0) * tanh_(pj);
        float hn = sigm(po) * tanh_(cn);
        cst[i] = own ? cn : 0.0f;
        if (own) {
            int row = w * 16 + kg * 4 + i;
            hOut[row * 256 + hu] = f2b(hn);
        }
    }
}

__device__ __forceinline__ void finish_stage(f32x4 a0, f32x4 a1, const u16* axp, int col,
    float* cst, u16* hOut, int w, int l, int hu) {
    int n16 = l & 15, kg = l >> 4;
    float ax0[4], ax1[4];
#pragma unroll
    for (int i = 0; i < 4; ++i) {
        int row = w * 16 + kg * 4 + i;
        ax0[i] = b2f(axp[(long)row * 3072 + col + n16]);
        ax1[i] = b2f(axp[(long)row * 3072 + col + 16 + n16]);
    }
    gate_update(a0, a1, ax0, ax1, cst, hOut, w, l, hu);
}

// 8 k-steps (256-dim) of both accumulator tiles, A from global h, B from LDS
__device__ __forceinline__ void acc8(const u16* h, int arow, const short8* bq,
    int i0, int i1, int l, f32x4& a0, f32x4& a1) {
#pragma unroll
    for (int ks = 0; ks < 8; ++ks) {
        short8 a = *(const short8*)(h + arow + ks * 32);
        a0 = mfma16(a, bq[(i0 + ks) * 64 + l], a0);
        a1 = mfma16(a, bq[(i1 + ks) * 64 + l], a1);
    }
}

__global__ __launch_bounds__(256, 1) void k_rec(
    const int* __restrict__ ids, const void* __restrict__ emb,
    const void* b0, const void* b1, const void* b2,
    void* wsv, void* outv, int chunk, int t0, int tc, int t0n, int tcn,
    long axstride, int first) {
    __shared__ short8 bq[4096];   // 64 fb * 64 lanes * 16B = 64KB (stages 1,2)
    __shared__ int sh_role, sh_rank;
    char* ws = (char*)wsv;
    int tid = threadIdx.x, l = tid & 63, w = tid >> 6;
    int isbf = *(const int*)(ws + O_FLAG);
    int* syn = (int*)(ws + O_SYNC + (long)chunk * 64);
    // ---- census & election: first XCD to accumulate NBLK arrivals wins ----
    if (tid == 0) {
        int xcc;
        asm volatile("s_getreg_b32 %0, hwreg(HW_REG_XCC_ID, 0, 8)" : "=s"(xcc));
        xcc &= 7;
        int r = __hip_atomic_fetch_add(syn + 2 + xcc, 1, __ATOMIC_RELAXED, __HIP_MEMORY_SCOPE_AGENT);
        int role = 1, rank = -1;
        if (r < NBLK) {
            if (r == NBLK - 1) {
                int exp = 0;
                __hip_atomic_compare_exchange_strong(syn + 10, &exp, xcc + 1,
                    __ATOMIC_RELAXED, __ATOMIC_RELAXED, __HIP_MEMORY_SCOPE_AGENT);
            }
            int wv;
            while ((wv = __hip_atomic_load(syn + 10, __ATOMIC_RELAXED, __HIP_MEMORY_SCOPE_AGENT)) == 0)
                __builtin_amdgcn_s_sleep(8);
            if (wv == xcc + 1) { role = 0; rank = r; }
        }
        if (role) rank = __hip_atomic_fetch_add(syn + 11, 1, __ATOMIC_RELAXED, __HIP_MEMORY_SCOPE_AGENT);
        sh_role = role; sh_rank = rank;
    }
    __syncthreads();
    int role = sh_role, rank = sh_rank;

    if (role) {   // ---- helper: next chunk's x-GEMM at low priority ----
        asm volatile("s_setprio 0");
        if (tcn > 0) {
            const short8* bpa = (const short8*)(ws + O_BPA);
            u16* axn = (u16*)(ws + O_AX) + (long)((chunk + 1) & 1) * axstride;
            for (int job = rank; job < 12 * tcn; job += NHELP) {
                int seg = job % 12, tl = job / 12;
                gemm_tile(ids, emb, b0, b1, b2, bpa, isbf, seg, t0n + tl,
                          axn + (long)tl * 196608);
            }
        }
        return;
    }
    asm volatile("s_setprio 3");
    // ---- worker ----
    const short8* bpr = (const short8*)(ws + O_BPR) + (long)rank * 80 * 64;
#pragma unroll
    for (int i = 0; i < 16; ++i) bq[i * 256 + tid] = bpr[16 * 64 + i * 256 + tid];
    short8 w0a[8], w0b[8];
#pragma unroll
    for (int ks = 0; ks < 8; ++ks) { w0a[ks] = bpr[ks * 64 + l]; w0b[ks] = bpr[(8 + ks) * 64 + l]; }
    u16* hbuf = (u16*)(ws + O_H);
    float* csave = (float*)(ws + O_C);
    const u16* axc = (const u16*)(ws + O_AX) + (long)(chunk & 1) * axstride;
    int n16 = l & 15, kg = l >> 4;
    int hu = rank * 8 + (n16 & 7);
    bool own = n16 < 8;
    float c0[4], c1[4], c2[4];
#pragma unroll
    for (int i = 0; i < 4; ++i) {
        int row = w * 16 + kg * 4 + i;
        if (first || !own) { c0[i] = 0.f; c1[i] = 0.f; c2[i] = 0.f; }
        else {
            c0[i] = csave[(0 * 64 + row) * 256 + hu];
            c1[i] = csave[(1 * 64 + row) * 256 + hu];
            c2[i] = csave[(2 * 64 + row) * 256 + hu];
        }
    }
    __syncthreads();
    int lph = 0;
    int arow = (w * 16 + n16) * 256 + kg * 8;
    for (int tl = 0; tl < tc; ++tl) {
        int t = t0 + tl, par = t & 1, prv = par ^ 1;
        const u16* axp = axc + (long)tl * 196608;
        const u16* h0p = hbuf + (0 * 2 + prv) * 16384; u16* h0c = hbuf + (0 * 2 + par) * 16384;
        const u16* h1p = hbuf + (1 * 2 + prv) * 16384; u16* h1c = hbuf + (1 * 2 + par) * 16384;
        const u16* h2p = hbuf + (2 * 2 + prv) * 16384; u16* h2c = hbuf + (2 * 2 + par) * 16384;
        // S0 (layer 0, K=256, reg weights) — h0(t-1) visible since bar1(t-1)
        f32x4 a0 = {0.f, 0.f, 0.f, 0.f}, a1 = {0.f, 0.f, 0.f, 0.f};
#pragma unroll
        for (int ks = 0; ks < 8; ++ks) {
            short8 a = *(const short8*)(h0p + arow + ks * 32);
            a0 = mfma16(a, w0a[ks], a0); a1 = mfma16(a, w0b[ks], a1);
        }
        finish_stage(a0, a1, axp, rank * 32, c0, h0c, w, l, hu);
        // partial S1: W1h x h1(t-1) half — independent of bar1
        f32x4 p10 = {0.f, 0.f, 0.f, 0.f}, p11 = {0.f, 0.f, 0.f, 0.f};
        acc8(h1p, arow, bq, 8, 24, l, p10, p11);
        gbar32(syn, &lph);                    // bar1: h0(t) exchange
        // finish S1: W1x' x h0(t) half
        acc8(h0c, arow, bq, 0, 16, l, p10, p11);
        finish_stage(p10, p11, axp, 1024 + rank * 32, c1, h1c, w, l, hu);
        // partial S2: W2h x h2(t-1) half (visible since bar1)
        f32x4 p20 = {0.f, 0.f, 0.f, 0.f}, p21 = {0.f, 0.f, 0.f, 0.f};
        acc8(h2p, arow, bq, 40, 56, l, p20, p21);
        gbar32(syn, &lph);                    // bar2: h1(t) exchange
        // finish S2: W2x' x h1(t) half
        acc8(h1c, arow, bq, 32, 48, l, p20, p21);
        finish_stage(p20, p21, axp, 2048 + rank * 32, c2, h2c, w, l, hu);
        // S2(t)/S0(t+1) hazards covered by next step's two barriers
    }
    if (own) {
        int fpar = (t0 + tc - 1) & 1;
#pragma unroll
        for (int i = 0; i < 4; ++i) {
            int row = w * 16 + kg * 4 + i;
            csave[(0 * 64 + row) * 256 + hu] = c0[i];
            csave[(1 * 64 + row) * 256 + hu] = c1[i];
            csave[(2 * 64 + row) * 256 + hu] = c2[i];
            float h0v = b2f(hbuf[(0 * 2 + fpar) * 16384 + row * 256 + hu]);
            float h1v = b2f(hbuf[(1 * 2 + fpar) * 16384 + row * 256 + hu]);
            float h2v = b2f(hbuf[(2 * 2 + fpar) * 16384 + row * 256 + hu]);
            if (isbf) {
                u16* o = (u16*)outv;
                o[row * 1536 + 0 + hu] = f2b(c0[i]);
                o[row * 1536 + 256 + hu] = f2b(h0v);
                o[row * 1536 + 512 + hu] = f2b(c1[i]);
                o[row * 1536 + 768 + hu] = f2b(h1v);
                o[row * 1536 + 1024 + hu] = f2b(c2[i]);
                o[row * 1536 + 1280 + hu] = f2b(h2v);
            } else {
                float* o = (float*)outv;
                o[row * 1536 + 0 + hu] = c0[i];
                o[row * 1536 + 256 + hu] = h0v;
                o[row * 1536 + 512 + hu] = c1[i];
                o[row * 1536 + 768 + hu] = h1v;
                o[row * 1536 + 1024 + hu] = c2[i];
                o[row * 1536 + 1280 + hu] = h2v;
            }
        }
    }
}

extern "C" void kernel_launch(void* const* d_in, const int* in_sizes, int n_in,
                              void* d_out, int out_size, void* d_ws, size_t ws_size,
                              hipStream_t stream) {
    const int* ids = (const int*)d_in[0];
    const void* emb = d_in[1];
    const void* W0x = d_in[2]; const void* W0h = d_in[3]; const void* b0 = d_in[4];
    const void* W1x = d_in[5]; const void* W1h = d_in[6]; const void* b1 = d_in[7];
    const void* W2x = d_in[8]; const void* W2h = d_in[9]; const void* b2 = d_in[10];
    char* ws = (char*)d_ws;

    long avail = (long)ws_size - O_AX;
    long per_t = 64L * 3072 * 2;
    int tc_max = (int)(avail / (2 * per_t));   // double-buffered Ax
    if (tc_max > TSEQ) tc_max = TSEQ;
    if (tc_max < 1) tc_max = 1;
    long axstride = (long)tc_max * 196608;     // elements per Ax buffer
    int nck = (TSEQ + tc_max - 1) / tc_max;

    hipMemsetAsync(ws + O_SYNC, 0, 16384, stream);
    hipMemsetAsync(ws + O_H, 0, 196608, stream);
    k_detect<<<1, 256, 0, stream>>>((const u32*)emb, (int*)(ws + O_FLAG));
    k_pack_a<<<384, 256, 0, stream>>>(W0x, W1x, W2x, d_ws);
    k_pack_r<<<640, 256, 0, stream>>>(W0h, W1x, W1h, W2x, W2h, d_ws);

    int tc0 = (TSEQ < tc_max) ? TSEQ : tc_max;
    { dim3 g(12, (unsigned)tc0);
      k_gemm_x<<<g, 256, 0, stream>>>(ids, emb, b0, b1, b2, d_ws, 0); }

    for (int c = 0; c < nck; ++c) {
        int t0 = c * tc_max;
        int tc = TSEQ - t0; if (tc > tc_max) tc = tc_max;
        int t0n = t0 + tc;
        int tcn = 0;
        if (c + 1 < nck) { tcn = TSEQ - t0n; if (tcn > tc_max) tcn = tc_max; }
        k_rec<<<GRID_REC, 256, 0, stream>>>(ids, emb, b0, b1, b2, d_ws, d_out,
                                            c, t0, tc, t0n, tcn, axstride, c == 0);
    }
}

// Round 4
// 10531.661 us; speedup vs baseline: 2.0263x; 1.1051x over previous
//
#include <hip/hip_runtime.h>
#include <hip/hip_bf16.h>

// DeepLSTM on MI355X — R4: R3's wavefront layer-pipelining (1 barrier/superstep) +
// blocked Ax, with the barrier rebuilt on proven agent-scope atomics:
//   arrival: per-worker relaxed AGENT atomic store to its own 64B-padded flag (no RMW serialization)
//   wait:    32 lanes poll 32 flags with relaxed AGENT atomic loads (parallel MALL reads)
//   acquire: buffer_inv (L1 invalidate; h-data lives in the shared same-XCD L2)
// Superstep s computes S0(t=s), S1(t=s-1), S2(t=s-2); all reads parity s^1, writes parity s.

typedef __attribute__((ext_vector_type(8))) short short8;
typedef __attribute__((ext_vector_type(4))) float f32x4;
typedef unsigned short u16;
typedef unsigned int u32;

#define TSEQ 1000
#define NBLK 32
#define GRID_REC 256
#define NHELP (GRID_REC - NBLK)

// ws layout (bytes)
#define O_FLAG 0L
#define O_SYNC 512L      // 256 chunk slots * 4096B (election @+0, flags @+1024, stride 64B)
#define O_H    1049088L  // h[3][2][64][256] bf16 = 196608
#define O_C    1245696L  // c_save[3][64][256] f32 = 196608
#define O_BPA  1442304L  // packed phase-A B: 192 tiles * 8 ks * 64 lanes * 16B
#define O_BPR  3015168L  // packed rec B: 32 rank * 80 fb * 64 lanes * 16B
#define O_AX   5636608L  // 2 buffers of tc_max * 196608 bf16 ([t][3][32][64*32] blocked)

__device__ __forceinline__ u16 f2b(float v) {
    __hip_bfloat16 h = __float2bfloat16(v);
    u16 u; __builtin_memcpy(&u, &h, 2); return u;
}
__device__ __forceinline__ float b2f(u16 u) {
    __hip_bfloat16 h; __builtin_memcpy(&h, &u, 2); return __bfloat162float(h);
}
__device__ __forceinline__ float rdw(const void* p, long i, int isbf) {
    return isbf ? b2f(((const u16*)p)[i]) : ((const float*)p)[i];
}
__device__ __forceinline__ float sigm(float x) { return 1.0f / (1.0f + __expf(-x)); }
__device__ __forceinline__ float tanh_(float x) { return 1.0f - 2.0f / (1.0f + __expf(2.0f * x)); }
__device__ __forceinline__ f32x4 mfma16(short8 a, short8 b, f32x4 c) {
    return __builtin_amdgcn_mfma_f32_16x16x32_bf16(a, b, c, 0, 0, 0);
}
__device__ __forceinline__ void acq_fence() {
    asm volatile("buffer_inv\ns_waitcnt vmcnt(0)" ::: "memory");
}

// ---------- dtype detect ----------
__global__ void k_detect(const u32* __restrict__ embw, int* flag) {
    __shared__ int cnt[256];
    int tid = threadIdx.x, c = 0;
    for (int i = 0; i < 16; ++i) {
        u32 w = embw[tid * 16 + i];
        u32 e = (w >> 7) & 0xFF;
        c += (e >= 110 && e <= 126) ? 1 : 0;
    }
    cnt[tid] = c; __syncthreads();
    for (int s = 128; s > 0; s >>= 1) { if (tid < s) cnt[tid] += cnt[tid + s]; __syncthreads(); }
    if (tid == 0) flag[0] = (cnt[0] > 2048) ? 1 : 0;
}

// ---------- pack phase-A B ----------
__global__ void k_pack_a(const void* W0x, const void* W1x, const void* W2x, void* wsv) {
    char* ws = (char*)wsv;
    int isbf = *(const int*)(ws + O_FLAG);
    int l = threadIdx.x & 63, w = threadIdx.x >> 6;
    int gid = blockIdx.x * 4 + w;          // 0..1535 = tile*8 + ks
    int tile = gid >> 3, ks = gid & 7;
    int L = tile >> 6, wi = tile & 63, bk = wi >> 1, half = wi & 1;
    int n16 = l & 15, g = half * 2 + (n16 >> 3), u = n16 & 7;
    int n = g * 256 + bk * 8 + u;
    const void* W = (L == 0) ? W0x : ((L == 1) ? W1x : W2x);
    union { u16 us[8]; short8 v; } tmp;
#pragma unroll
    for (int j = 0; j < 8; ++j) {
        int k = ks * 32 + (l >> 4) * 8 + j;
        tmp.us[j] = f2b(rdw(W, (long)k * 1024 + n, isbf));
    }
    ((short8*)(ws + O_BPA))[(long)(tile * 8 + ks) * 64 + l] = tmp.v;
}

// ---------- pack recurrent B ----------
__global__ void k_pack_r(const void* W0h, const void* W1x, const void* W1h,
                         const void* W2x, const void* W2h, void* wsv) {
    char* ws = (char*)wsv;
    int isbf = *(const int*)(ws + O_FLAG);
    int l = threadIdx.x & 63, w = threadIdx.x >> 6;
    int gid = blockIdx.x * 4 + w;          // 0..2559 = rank*80 + fb
    int bk = gid / 80, fb = gid % 80;
    int s, nt, ks;
    if (fb < 16) { s = 0; nt = fb >> 3; ks = fb & 7; }
    else if (fb < 48) { s = 1; int f = fb - 16; nt = f >> 4; ks = f & 15; }
    else { s = 2; int f = fb - 48; nt = f >> 4; ks = f & 15; }
    int n16 = l & 15, g = nt * 2 + (n16 >> 3), u = n16 & 7;
    int n = g * 256 + bk * 8 + u;
    union { u16 us[8]; short8 v; } tmp;
#pragma unroll
    for (int j = 0; j < 8; ++j) {
        int k = ks * 32 + (l >> 4) * 8 + j;
        float v;
        if (s == 0) v = rdw(W0h, (long)k * 1024 + n, isbf);
        else if (s == 1) v = (k < 256) ? rdw(W1x, (long)(256 + k) * 1024 + n, isbf)
                                       : rdw(W1h, (long)(k - 256) * 1024 + n, isbf);
        else v = (k < 256) ? rdw(W2x, (long)(256 + k) * 1024 + n, isbf)
                           : rdw(W2h, (long)(k - 256) * 1024 + n, isbf);
        tmp.us[j] = f2b(v);
    }
    ((short8*)(ws + O_BPR))[(long)bk * 80 * 64 + (long)fb * 64 + l] = tmp.v;
}

// ---------- x-GEMM tile: 64 batch rows x 256 gate cols at timestep t ----------
// Output layout (per t): [L(3)][rank(32)][row(64)*32 + half*16 + n16]  (4KB blocks)
__device__ __forceinline__ void gemm_tile(const int* __restrict__ ids, const void* __restrict__ emb,
    const void* b0, const void* b1, const void* b2, const short8* __restrict__ bpa,
    int isbf, int seg, int t, u16* __restrict__ axp) {
    int tid = threadIdx.x, l = tid & 63, w = tid >> 6;
    int n16 = l & 15, kg = l >> 4;
    short8 a[4][8];
#pragma unroll
    for (int mt = 0; mt < 4; ++mt) {
        int b = mt * 16 + n16;
        long id = ids[b * TSEQ + t];
        if (isbf) {
            const u16* ep = (const u16*)emb + id * 256;
#pragma unroll
            for (int ks = 0; ks < 8; ++ks)
                a[mt][ks] = *(const short8*)(ep + ks * 32 + kg * 8);
        } else {
            const float* ep = (const float*)emb + id * 256;
#pragma unroll
            for (int ks = 0; ks < 8; ++ks) {
                f32x4 v0 = *(const f32x4*)(ep + ks * 32 + kg * 8);
                f32x4 v1 = *(const f32x4*)(ep + ks * 32 + kg * 8 + 4);
                union { u16 us[8]; short8 v; } tmp;
#pragma unroll
                for (int j = 0; j < 4; ++j) { tmp.us[j] = f2b(v0[j]); tmp.us[4 + j] = f2b(v1[j]); }
                a[mt][ks] = tmp.v;
            }
        }
    }
#pragma unroll
    for (int nt = 0; nt < 4; ++nt) {
        int tile = seg * 16 + w * 4 + nt;
        f32x4 acc[4];
#pragma unroll
        for (int mt = 0; mt < 4; ++mt) acc[mt] = (f32x4){0.f, 0.f, 0.f, 0.f};
#pragma unroll
        for (int ks = 0; ks < 8; ++ks) {
            short8 bb = bpa[(long)(tile * 8 + ks) * 64 + l];
#pragma unroll
            for (int mt = 0; mt < 4; ++mt) acc[mt] = mfma16(a[mt][ks], bb, acc[mt]);
        }
        int L = tile >> 6, wi = tile & 63, bkk = wi >> 1, half = wi & 1;
        int g = half * 2 + (n16 >> 3), u = n16 & 7;
        const void* bias = (L == 0) ? b0 : ((L == 1) ? b1 : b2);
        float bv = rdw(bias, g * 256 + bkk * 8 + u, isbf);
        long base = (long)(L * 32 + bkk) * 2048 + half * 16 + n16;
#pragma unroll
        for (int mt = 0; mt < 4; ++mt)
#pragma unroll
            for (int i = 0; i < 4; ++i) {
                int row = mt * 16 + kg * 4 + i;
                axp[base + (long)row * 32] = f2b(acc[mt][i] + bv);
            }
    }
}

__global__ __launch_bounds__(256, 1) void k_gemm_x(
    const int* __restrict__ ids, const void* __restrict__ emb,
    const void* b0, const void* b1, const void* b2, void* wsv, int t0) {
    char* ws = (char*)wsv;
    int isbf = *(const int*)(ws + O_FLAG);
    const short8* bpa = (const short8*)(ws + O_BPA);
    u16* ax = (u16*)(ws + O_AX);   // buffer 0
    gemm_tile(ids, emb, b0, b1, b2, bpa, isbf, blockIdx.x, t0 + blockIdx.y,
              ax + (long)blockIdx.y * 196608);
}

// ---------- barrier wait: 32 lanes poll 32 padded flags (agent relaxed loads) ----------
__device__ __forceinline__ void xbar_wait(u32* flags, u32 p, int l) {
    u32* fp = flags + (l & 31) * 16;   // one flag per 64B line
    for (int it = 0; it < (1 << 22); ++it) {   // bounded spin: fail loud, not hung
        u32 v = __hip_atomic_load(fp, __ATOMIC_RELAXED, __HIP_MEMORY_SCOPE_AGENT);
        if (__all((int)(v >= p))) return;
        __builtin_amdgcn_s_sleep(2);
    }
}

__device__ __forceinline__ void gate_update(f32x4 acc0, f32x4 acc1,
    const float* ax0, const float* ax1, float* cst, u16* hOut, int w, int l, int hu) {
    int n16 = l & 15, kg = l >> 4;
    bool own = n16 < 8;
#pragma unroll
    for (int i = 0; i < 4; ++i) {
        float g0 = acc0[i] + ax0[i];   // own: i-gate | partner: j-gate
        float g1 = acc1[i] + ax1[i];   // own: f-gate | partner: o-gate
        float pj = __shfl_xor(g0, 8, 64);
        float po = __shfl_xor(g1, 8, 64);
        float cn = sigm(g1) * cst[i] + sigm(g0) * tanh_(pj);
        float hn = sigm(po) * tanh_(cn);
        cst[i] = own ? cn : 0.0f;
        if (own) {
            int row = w * 16 + kg * 4 + i;
            hOut[row * 256 + hu] = f2b(hn);
        }
    }
}

// axs: pre-offset blocked Ax slice ([row*32 + {n16 | 16+n16}])
__device__ __forceinline__ void finish_stage(f32x4 a0, f32x4 a1, const u16* axs,
    float* cst, u16* hOut, int w, int l, int hu) {
    int n16 = l & 15, kg = l >> 4;
    float ax0[4], ax1[4];
#pragma unroll
    for (int i = 0; i < 4; ++i) {
        int row = w * 16 + kg * 4 + i;
        ax0[i] = b2f(axs[row * 32 + n16]);
        ax1[i] = b2f(axs[row * 32 + 16 + n16]);
    }
    gate_update(a0, a1, ax0, ax1, cst, hOut, w, l, hu);
}

__device__ __forceinline__ void acc8(const u16* h, int arow, const short8* bq,
    int i0, int i1, int l, f32x4& a0, f32x4& a1) {
#pragma unroll
    for (int ks = 0; ks < 8; ++ks) {
        short8 a = *(const short8*)(h + arow + ks * 32);
        a0 = mfma16(a, bq[(i0 + ks) * 64 + l], a0);
        a1 = mfma16(a, bq[(i1 + ks) * 64 + l], a1);
    }
}

__global__ __launch_bounds__(256, 1) void k_rec(
    const int* __restrict__ ids, const void* __restrict__ emb,
    const void* b0, const void* b1, const void* b2,
    void* wsv, void* outv, int chunk, int t0, int tc, int t0n, int tcn,
    long axstride, int first, int last) {
    __shared__ short8 bq[4096];
    __shared__ int sh_role, sh_rank;
    char* ws = (char*)wsv;
    int tid = threadIdx.x, l = tid & 63, w = tid >> 6;
    int isbf = *(const int*)(ws + O_FLAG);
    int* syn = (int*)(ws + O_SYNC + (long)chunk * 4096);
    u32* flags = (u32*)((char*)syn + 1024);
    // ---- census & election (once per dispatch; agent atomics OK here) ----
    if (tid == 0) {
        int xcc;
        asm volatile("s_getreg_b32 %0, hwreg(HW_REG_XCC_ID, 0, 8)" : "=s"(xcc));
        xcc &= 7;
        int r = __hip_atomic_fetch_add(syn + 2 + xcc, 1, __ATOMIC_RELAXED, __HIP_MEMORY_SCOPE_AGENT);
        int role = 1, rank = -1;
        if (r < NBLK) {
            if (r == NBLK - 1) {
                int exp = 0;
                __hip_atomic_compare_exchange_strong(syn + 10, &exp, xcc + 1,
                    __ATOMIC_RELAXED, __ATOMIC_RELAXED, __HIP_MEMORY_SCOPE_AGENT);
            }
            int wv;
            while ((wv = __hip_atomic_load(syn + 10, __ATOMIC_RELAXED, __HIP_MEMORY_SCOPE_AGENT)) == 0)
                __builtin_amdgcn_s_sleep(8);
            if (wv == xcc + 1) { role = 0; rank = r; }
        }
        if (role) rank = __hip_atomic_fetch_add(syn + 11, 1, __ATOMIC_RELAXED, __HIP_MEMORY_SCOPE_AGENT);
        sh_role = role; sh_rank = rank;
    }
    __syncthreads();
    int role = sh_role, rank = sh_rank;

    if (role) {   // ---- helper: next chunk's x-GEMM ----
        asm volatile("s_setprio 0");
        if (tcn > 0) {
            const short8* bpa = (const short8*)(ws + O_BPA);
            u16* axn = (u16*)(ws + O_AX) + (long)((chunk + 1) & 1) * axstride;
            for (int job = rank; job < 12 * tcn; job += NHELP) {
                int seg = job % 12, tl = job / 12;
                gemm_tile(ids, emb, b0, b1, b2, bpa, isbf, seg, t0n + tl,
                          axn + (long)tl * 196608);
            }
        }
        return;
    }
    asm volatile("s_setprio 3");
    // ---- worker ----
    const short8* bpr = (const short8*)(ws + O_BPR) + (long)rank * 80 * 64;
#pragma unroll
    for (int i = 0; i < 16; ++i) bq[i * 256 + tid] = bpr[16 * 64 + i * 256 + tid];
    short8 w0a[8], w0b[8];
#pragma unroll
    for (int ks = 0; ks < 8; ++ks) { w0a[ks] = bpr[ks * 64 + l]; w0b[ks] = bpr[(8 + ks) * 64 + l]; }
    u16* hbuf = (u16*)(ws + O_H);
    float* csave = (float*)(ws + O_C);
    const u16* axc = (const u16*)(ws + O_AX) + (long)(chunk & 1) * axstride;
    int n16 = l & 15, kg = l >> 4;
    int hu = rank * 8 + (n16 & 7);
    bool own = n16 < 8;
    float c0[4], c1[4], c2[4];
#pragma unroll
    for (int i = 0; i < 4; ++i) {
        int row = w * 16 + kg * 4 + i;
        if (first || !own) { c0[i] = 0.f; c1[i] = 0.f; c2[i] = 0.f; }
        else {
            c0[i] = csave[(0 * 64 + row) * 256 + hu];
            c1[i] = csave[(1 * 64 + row) * 256 + hu];
            c2[i] = csave[(2 * 64 + row) * 256 + hu];
        }
    }
    __syncthreads();
    int lph = 0;
    int arow = (w * 16 + n16) * 256 + kg * 8;
    const int sEnd = t0 + tc + 2;
    for (int s = t0; s < sEnd; ++s) {
        int par = s & 1, prv = par ^ 1;
        const u16* h0p = hbuf + (0 * 2 + prv) * 16384; u16* h0c = hbuf + (0 * 2 + par) * 16384;
        const u16* h1p = hbuf + (1 * 2 + prv) * 16384; u16* h1c = hbuf + (1 * 2 + par) * 16384;
        const u16* h2p = hbuf + (2 * 2 + prv) * 16384; u16* h2c = hbuf + (2 * 2 + par) * 16384;
        // S0 at t=s : reads h0(s-1) [prv]
        if (s < t0 + tc) {
            f32x4 a0 = {0.f, 0.f, 0.f, 0.f}, a1 = {0.f, 0.f, 0.f, 0.f};
#pragma unroll
            for (int ks = 0; ks < 8; ++ks) {
                short8 a = *(const short8*)(h0p + arow + ks * 32);
                a0 = mfma16(a, w0a[ks], a0); a1 = mfma16(a, w0b[ks], a1);
            }
            finish_stage(a0, a1, axc + (long)(s - t0) * 196608 + (long)rank * 2048,
                         c0, h0c, w, l, hu);
        }
        // S1 at t=s-1 : reads h0(s-1) [prv], h1(s-2) [prv]
        if (s > t0 && s <= t0 + tc) {
            f32x4 a0 = {0.f, 0.f, 0.f, 0.f}, a1 = {0.f, 0.f, 0.f, 0.f};
            acc8(h0p, arow, bq, 0, 16, l, a0, a1);
            acc8(h1p, arow, bq, 8, 24, l, a0, a1);
            finish_stage(a0, a1, axc + (long)(s - 1 - t0) * 196608 + (long)(32 + rank) * 2048,
                         c1, h1c, w, l, hu);
        }
        // S2 at t=s-2 : reads h1(s-2) [prv], h2(s-3) [prv]
        if (s > t0 + 1) {
            f32x4 a0 = {0.f, 0.f, 0.f, 0.f}, a1 = {0.f, 0.f, 0.f, 0.f};
            acc8(h1p, arow, bq, 32, 48, l, a0, a1);
            acc8(h2p, arow, bq, 40, 56, l, a0, a1);
            finish_stage(a0, a1, axc + (long)(s - 2 - t0) * 196608 + (long)(64 + rank) * 2048,
                         c2, h2c, w, l, hu);
        }
        if (s + 1 < sEnd) {
            ++lph;
            __syncthreads();   // all waves drain vmcnt before s_barrier -> h stores in L2
            if (tid == 0) {
                asm volatile("s_waitcnt vmcnt(0)" ::: "memory");
                __hip_atomic_store(flags + rank * 16, (u32)lph, __ATOMIC_RELAXED,
                                   __HIP_MEMORY_SCOPE_AGENT);
            }
            xbar_wait(flags, (u32)lph, l);
            acq_fence();
        }
    }
    if (own) {
#pragma unroll
        for (int i = 0; i < 4; ++i) {
            int row = w * 16 + kg * 4 + i;
            csave[(0 * 64 + row) * 256 + hu] = c0[i];
            csave[(1 * 64 + row) * 256 + hu] = c1[i];
            csave[(2 * 64 + row) * 256 + hu] = c2[i];
        }
        if (last) {
            int f0 = (TSEQ - 1) & 1, f1 = TSEQ & 1, f2 = (TSEQ + 1) & 1;
#pragma unroll
            for (int i = 0; i < 4; ++i) {
                int row = w * 16 + kg * 4 + i;
                float h0v = b2f(hbuf[(0 * 2 + f0) * 16384 + row * 256 + hu]);
                float h1v = b2f(hbuf[(1 * 2 + f1) * 16384 + row * 256 + hu]);
                float h2v = b2f(hbuf[(2 * 2 + f2) * 16384 + row * 256 + hu]);
                if (isbf) {
                    u16* o = (u16*)outv;
                    o[row * 1536 + 0 + hu] = f2b(c0[i]);
                    o[row * 1536 + 256 + hu] = f2b(h0v);
                    o[row * 1536 + 512 + hu] = f2b(c1[i]);
                    o[row * 1536 + 768 + hu] = f2b(h1v);
                    o[row * 1536 + 1024 + hu] = f2b(c2[i]);
                    o[row * 1536 + 1280 + hu] = f2b(h2v);
                } else {
                    float* o = (float*)outv;
                    o[row * 1536 + 0 + hu] = c0[i];
                    o[row * 1536 + 256 + hu] = h0v;
                    o[row * 1536 + 512 + hu] = c1[i];
                    o[row * 1536 + 768 + hu] = h1v;
                    o[row * 1536 + 1024 + hu] = c2[i];
                    o[row * 1536 + 1280 + hu] = h2v;
                }
            }
        }
    }
}

extern "C" void kernel_launch(void* const* d_in, const int* in_sizes, int n_in,
                              void* d_out, int out_size, void* d_ws, size_t ws_size,
                              hipStream_t stream) {
    const int* ids = (const int*)d_in[0];
    const void* emb = d_in[1];
    const void* W0x = d_in[2]; const void* W0h = d_in[3]; const void* b0 = d_in[4];
    const void* W1x = d_in[5]; const void* W1h = d_in[6]; const void* b1 = d_in[7];
    const void* W2x = d_in[8]; const void* W2h = d_in[9]; const void* b2 = d_in[10];
    char* ws = (char*)d_ws;

    long avail = (long)ws_size - O_AX;
    long per_t = 64L * 3072 * 2;
    int tc_max = (int)(avail / (2 * per_t));   // double-buffered Ax
    if (tc_max > TSEQ) tc_max = TSEQ;
    if (tc_max < 4) tc_max = 4;                // keep nck <= 250 (slots: 256)
    long axstride = (long)tc_max * 196608;
    int nck = (TSEQ + tc_max - 1) / tc_max;

    hipMemsetAsync(ws + O_SYNC, 0, 1048576, stream);
    hipMemsetAsync(ws + O_H, 0, 196608, stream);
    k_detect<<<1, 256, 0, stream>>>((const u32*)emb, (int*)(ws + O_FLAG));
    k_pack_a<<<384, 256, 0, stream>>>(W0x, W1x, W2x, d_ws);
    k_pack_r<<<640, 256, 0, stream>>>(W0h, W1x, W1h, W2x, W2h, d_ws);

    int tc0 = (TSEQ < tc_max) ? TSEQ : tc_max;
    { dim3 g(12, (unsigned)tc0);
      k_gemm_x<<<g, 256, 0, stream>>>(ids, emb, b0, b1, b2, d_ws, 0); }

    for (int c = 0; c < nck; ++c) {
        int t0 = c * tc_max;
        int tc = TSEQ - t0; if (tc > tc_max) tc = tc_max;
        int t0n = t0 + tc;
        int tcn = 0;
        if (c + 1 < nck) { tcn = TSEQ - t0n; if (tcn > tc_max) tcn = tc_max; }
        k_rec<<<GRID_REC, 256, 0, stream>>>(ids, emb, b0, b1, b2, d_ws, d_out,
                                            c, t0, tc, t0n, tcn, axstride,
                                            c == 0, t0 + tc == TSEQ);
    }
}

// Round 5
// 9950.351 us; speedup vs baseline: 2.1446x; 1.0584x over previous
//
#include <hip/hip_runtime.h>
#include <hip/hip_bf16.h>

// DeepLSTM on MI355X — R5: barrier de-contention.
//   R4 post-mortem: per-step cost ~10.7us dominated by MALL queueing from 128 waves
//   polling agent-scope flags. R5: (1) wave0-only polls; (2) flags live in the
//   workers' shared XCD L2 (normal volatile store + buffer_inv/volatile-load poll),
//   with a periodic agent-atomic fallback for safety (flag stored both ways);
//   (3) Ax gate-bias prefetched at superstep top (off the h critical path).
// Superstep s computes S0(t=s), S1(t=s-1), S2(t=s-2); reads parity s^1, writes parity s.

typedef __attribute__((ext_vector_type(8))) short short8;
typedef __attribute__((ext_vector_type(4))) float f32x4;
typedef unsigned short u16;
typedef unsigned int u32;

#define TSEQ 1000
#define NBLK 32
#define GRID_REC 256
#define NHELP (GRID_REC - NBLK)

// ws layout (bytes). Sync slot (per chunk, stride 6144): election @+0,
// L2 flags @+1024 (32 x 64B), atomic fallback flags @+3072 (32 x 64B).
#define O_FLAG 0L
#define O_SYNC 512L
#define O_H    1573376L  // h[3][2][64][256] bf16 = 196608
#define O_C    1769984L  // c_save[3][64][256] f32 = 196608
#define O_BPA  1966592L  // packed phase-A B: 192 tiles * 8 ks * 64 lanes * 16B
#define O_BPR  3539456L  // packed rec B: 32 rank * 80 fb * 64 lanes * 16B
#define O_AX   6160896L  // 2 buffers of tc_max * 196608 bf16 ([t][3][32][64*32] blocked)

__device__ __forceinline__ u16 f2b(float v) {
    __hip_bfloat16 h = __float2bfloat16(v);
    u16 u; __builtin_memcpy(&u, &h, 2); return u;
}
__device__ __forceinline__ float b2f(u16 u) {
    __hip_bfloat16 h; __builtin_memcpy(&h, &u, 2); return __bfloat162float(h);
}
__device__ __forceinline__ float rdw(const void* p, long i, int isbf) {
    return isbf ? b2f(((const u16*)p)[i]) : ((const float*)p)[i];
}
__device__ __forceinline__ float sigm(float x) { return 1.0f / (1.0f + __expf(-x)); }
__device__ __forceinline__ float tanh_(float x) { return 1.0f - 2.0f / (1.0f + __expf(2.0f * x)); }
__device__ __forceinline__ f32x4 mfma16(short8 a, short8 b, f32x4 c) {
    return __builtin_amdgcn_mfma_f32_16x16x32_bf16(a, b, c, 0, 0, 0);
}

// ---------- dtype detect ----------
__global__ void k_detect(const u32* __restrict__ embw, int* flag) {
    __shared__ int cnt[256];
    int tid = threadIdx.x, c = 0;
    for (int i = 0; i < 16; ++i) {
        u32 w = embw[tid * 16 + i];
        u32 e = (w >> 7) & 0xFF;
        c += (e >= 110 && e <= 126) ? 1 : 0;
    }
    cnt[tid] = c; __syncthreads();
    for (int s = 128; s > 0; s >>= 1) { if (tid < s) cnt[tid] += cnt[tid + s]; __syncthreads(); }
    if (tid == 0) flag[0] = (cnt[0] > 2048) ? 1 : 0;
}

// ---------- pack phase-A B ----------
__global__ void k_pack_a(const void* W0x, const void* W1x, const void* W2x, void* wsv) {
    char* ws = (char*)wsv;
    int isbf = *(const int*)(ws + O_FLAG);
    int l = threadIdx.x & 63, w = threadIdx.x >> 6;
    int gid = blockIdx.x * 4 + w;          // 0..1535 = tile*8 + ks
    int tile = gid >> 3, ks = gid & 7;
    int L = tile >> 6, wi = tile & 63, bk = wi >> 1, half = wi & 1;
    int n16 = l & 15, g = half * 2 + (n16 >> 3), u = n16 & 7;
    int n = g * 256 + bk * 8 + u;
    const void* W = (L == 0) ? W0x : ((L == 1) ? W1x : W2x);
    union { u16 us[8]; short8 v; } tmp;
#pragma unroll
    for (int j = 0; j < 8; ++j) {
        int k = ks * 32 + (l >> 4) * 8 + j;
        tmp.us[j] = f2b(rdw(W, (long)k * 1024 + n, isbf));
    }
    ((short8*)(ws + O_BPA))[(long)(tile * 8 + ks) * 64 + l] = tmp.v;
}

// ---------- pack recurrent B ----------
__global__ void k_pack_r(const void* W0h, const void* W1x, const void* W1h,
                         const void* W2x, const void* W2h, void* wsv) {
    char* ws = (char*)wsv;
    int isbf = *(const int*)(ws + O_FLAG);
    int l = threadIdx.x & 63, w = threadIdx.x >> 6;
    int gid = blockIdx.x * 4 + w;          // 0..2559 = rank*80 + fb
    int bk = gid / 80, fb = gid % 80;
    int s, nt, ks;
    if (fb < 16) { s = 0; nt = fb >> 3; ks = fb & 7; }
    else if (fb < 48) { s = 1; int f = fb - 16; nt = f >> 4; ks = f & 15; }
    else { s = 2; int f = fb - 48; nt = f >> 4; ks = f & 15; }
    int n16 = l & 15, g = nt * 2 + (n16 >> 3), u = n16 & 7;
    int n = g * 256 + bk * 8 + u;
    union { u16 us[8]; short8 v; } tmp;
#pragma unroll
    for (int j = 0; j < 8; ++j) {
        int k = ks * 32 + (l >> 4) * 8 + j;
        float v;
        if (s == 0) v = rdw(W0h, (long)k * 1024 + n, isbf);
        else if (s == 1) v = (k < 256) ? rdw(W1x, (long)(256 + k) * 1024 + n, isbf)
                                       : rdw(W1h, (long)(k - 256) * 1024 + n, isbf);
        else v = (k < 256) ? rdw(W2x, (long)(256 + k) * 1024 + n, isbf)
                           : rdw(W2h, (long)(k - 256) * 1024 + n, isbf);
        tmp.us[j] = f2b(v);
    }
    ((short8*)(ws + O_BPR))[(long)bk * 80 * 64 + (long)fb * 64 + l] = tmp.v;
}

// ---------- x-GEMM tile: 64 batch rows x 256 gate cols at timestep t ----------
// Output layout (per t): [L(3)][rank(32)][row(64)*32 + half*16 + n16]  (4KB blocks)
__device__ __forceinline__ void gemm_tile(const int* __restrict__ ids, const void* __restrict__ emb,
    const void* b0, const void* b1, const void* b2, const short8* __restrict__ bpa,
    int isbf, int seg, int t, u16* __restrict__ axp) {
    int tid = threadIdx.x, l = tid & 63, w = tid >> 6;
    int n16 = l & 15, kg = l >> 4;
    short8 a[4][8];
#pragma unroll
    for (int mt = 0; mt < 4; ++mt) {
        int b = mt * 16 + n16;
        long id = ids[b * TSEQ + t];
        if (isbf) {
            const u16* ep = (const u16*)emb + id * 256;
#pragma unroll
            for (int ks = 0; ks < 8; ++ks)
                a[mt][ks] = *(const short8*)(ep + ks * 32 + kg * 8);
        } else {
            const float* ep = (const float*)emb + id * 256;
#pragma unroll
            for (int ks = 0; ks < 8; ++ks) {
                f32x4 v0 = *(const f32x4*)(ep + ks * 32 + kg * 8);
                f32x4 v1 = *(const f32x4*)(ep + ks * 32 + kg * 8 + 4);
                union { u16 us[8]; short8 v; } tmp;
#pragma unroll
                for (int j = 0; j < 4; ++j) { tmp.us[j] = f2b(v0[j]); tmp.us[4 + j] = f2b(v1[j]); }
                a[mt][ks] = tmp.v;
            }
        }
    }
#pragma unroll
    for (int nt = 0; nt < 4; ++nt) {
        int tile = seg * 16 + w * 4 + nt;
        f32x4 acc[4];
#pragma unroll
        for (int mt = 0; mt < 4; ++mt) acc[mt] = (f32x4){0.f, 0.f, 0.f, 0.f};
#pragma unroll
        for (int ks = 0; ks < 8; ++ks) {
            short8 bb = bpa[(long)(tile * 8 + ks) * 64 + l];
#pragma unroll
            for (int mt = 0; mt < 4; ++mt) acc[mt] = mfma16(a[mt][ks], bb, acc[mt]);
        }
        int L = tile >> 6, wi = tile & 63, bkk = wi >> 1, half = wi & 1;
        int g = half * 2 + (n16 >> 3), u = n16 & 7;
        const void* bias = (L == 0) ? b0 : ((L == 1) ? b1 : b2);
        float bv = rdw(bias, g * 256 + bkk * 8 + u, isbf);
        long base = (long)(L * 32 + bkk) * 2048 + half * 16 + n16;
#pragma unroll
        for (int mt = 0; mt < 4; ++mt)
#pragma unroll
            for (int i = 0; i < 4; ++i) {
                int row = mt * 16 + kg * 4 + i;
                axp[base + (long)row * 32] = f2b(acc[mt][i] + bv);
            }
    }
}

__global__ __launch_bounds__(256, 1) void k_gemm_x(
    const int* __restrict__ ids, const void* __restrict__ emb,
    const void* b0, const void* b1, const void* b2, void* wsv, int t0) {
    char* ws = (char*)wsv;
    int isbf = *(const int*)(ws + O_FLAG);
    const short8* bpa = (const short8*)(ws + O_BPA);
    u16* ax = (u16*)(ws + O_AX);   // buffer 0
    gemm_tile(ids, emb, b0, b1, b2, bpa, isbf, blockIdx.x, t0 + blockIdx.y,
              ax + (long)blockIdx.y * 196608);
}

// ---------- superstep barrier: L2-local poll + agent-atomic fallback ----------
// arrival (tid0): volatile store to L2 flag + relaxed agent atomic store to fallback flag.
// wait (wave0 only): buffer_inv + volatile load of own line; every 16 iters also check
// the MALL fallback flag. Other waves park at __syncthreads.
__device__ __forceinline__ void barrier_step(char* slot, int rank, u32 p, int tid, int l, int w) {
    volatile u32* fl2 = (volatile u32*)(slot + 1024);
    u32* fat = (u32*)(slot + 3072);
    __syncthreads();            // drains each wave's vmcnt before s_barrier -> h stores in L2
    if (tid == 0) {
        fl2[rank * 16] = p;
        __hip_atomic_store(fat + rank * 16, p, __ATOMIC_RELAXED, __HIP_MEMORY_SCOPE_AGENT);
    }
    if (w == 0) {
        int idx = l & 31;
        volatile u32* myl2 = fl2 + idx * 16;
        u32* myat = fat + idx * 16;
        for (int it = 0; it < (1 << 20); ++it) {
            asm volatile("buffer_inv" ::: "memory");
            u32 v = *myl2;
            if (__all((int)(v >= p))) break;
            if ((it & 15) == 15) {
                u32 va = __hip_atomic_load(myat, __ATOMIC_RELAXED, __HIP_MEMORY_SCOPE_AGENT);
                if (__all((int)(va >= p))) break;
            }
            __builtin_amdgcn_s_sleep(1);
        }
    }
    __syncthreads();
    asm volatile("buffer_inv" ::: "memory");   // acquire: L1 invalidate before h reads
}

__device__ __forceinline__ void gate_update(f32x4 acc0, f32x4 acc1,
    const float* ax0, const float* ax1, float* cst, u16* hOut, int w, int l, int hu) {
    int n16 = l & 15, kg = l >> 4;
    bool own = n16 < 8;
#pragma unroll
    for (int i = 0; i < 4; ++i) {
        float g0 = acc0[i] + ax0[i];   // own: i-gate | partner: j-gate
        float g1 = acc1[i] + ax1[i];   // own: f-gate | partner: o-gate
        float pj = __shfl_xor(g0, 8, 64);
        float po = __shfl_xor(g1, 8, 64);
        float cn = sigm(g1) * cst[i] + sigm(g0) * tanh_(pj);
        float hn = sigm(po) * tanh_(cn);
        cst[i] = own ? cn : 0.0f;
        if (own) {
            int row = w * 16 + kg * 4 + i;
            hOut[row * 256 + hu] = f2b(hn);
        }
    }
}

// prefetch one stage's Ax slice into registers (h-independent)
__device__ __forceinline__ void loadax(float dst[2][4], const u16* axs, int n16, int w, int kg) {
#pragma unroll
    for (int i = 0; i < 4; ++i) {
        int row = w * 16 + kg * 4 + i;
        dst[0][i] = b2f(axs[row * 32 + n16]);
        dst[1][i] = b2f(axs[row * 32 + 16 + n16]);
    }
}

__device__ __forceinline__ void acc8(const u16* h, int arow, const short8* bq,
    int i0, int i1, int l, f32x4& a0, f32x4& a1) {
#pragma unroll
    for (int ks = 0; ks < 8; ++ks) {
        short8 a = *(const short8*)(h + arow + ks * 32);
        a0 = mfma16(a, bq[(i0 + ks) * 64 + l], a0);
        a1 = mfma16(a, bq[(i1 + ks) * 64 + l], a1);
    }
}

__global__ __launch_bounds__(256, 1) void k_rec(
    const int* __restrict__ ids, const void* __restrict__ emb,
    const void* b0, const void* b1, const void* b2,
    void* wsv, void* outv, int chunk, int t0, int tc, int t0n, int tcn,
    long axstride, int first, int last) {
    __shared__ short8 bq[4096];
    __shared__ int sh_role, sh_rank;
    char* ws = (char*)wsv;
    int tid = threadIdx.x, l = tid & 63, w = tid >> 6;
    int isbf = *(const int*)(ws + O_FLAG);
    char* slot = ws + O_SYNC + (long)chunk * 6144;
    int* syn = (int*)slot;
    // ---- census & election (once per dispatch; agent atomics OK here) ----
    if (tid == 0) {
        int xcc;
        asm volatile("s_getreg_b32 %0, hwreg(HW_REG_XCC_ID, 0, 8)" : "=s"(xcc));
        xcc &= 7;
        int r = __hip_atomic_fetch_add(syn + 2 + xcc, 1, __ATOMIC_RELAXED, __HIP_MEMORY_SCOPE_AGENT);
        int role = 1, rank = -1;
        if (r < NBLK) {
            if (r == NBLK - 1) {
                int exp = 0;
                __hip_atomic_compare_exchange_strong(syn + 10, &exp, xcc + 1,
                    __ATOMIC_RELAXED, __ATOMIC_RELAXED, __HIP_MEMORY_SCOPE_AGENT);
            }
            int wv;
            while ((wv = __hip_atomic_load(syn + 10, __ATOMIC_RELAXED, __HIP_MEMORY_SCOPE_AGENT)) == 0)
                __builtin_amdgcn_s_sleep(8);
            if (wv == xcc + 1) { role = 0; rank = r; }
        }
        if (role) rank = __hip_atomic_fetch_add(syn + 11, 1, __ATOMIC_RELAXED, __HIP_MEMORY_SCOPE_AGENT);
        sh_role = role; sh_rank = rank;
    }
    __syncthreads();
    int role = sh_role, rank = sh_rank;

    if (role) {   // ---- helper: next chunk's x-GEMM ----
        asm volatile("s_setprio 0");
        if (tcn > 0) {
            const short8* bpa = (const short8*)(ws + O_BPA);
            u16* axn = (u16*)(ws + O_AX) + (long)((chunk + 1) & 1) * axstride;
            for (int job = rank; job < 12 * tcn; job += NHELP) {
                int seg = job % 12, tl = job / 12;
                gemm_tile(ids, emb, b0, b1, b2, bpa, isbf, seg, t0n + tl,
                          axn + (long)tl * 196608);
            }
        }
        return;
    }
    asm volatile("s_setprio 3");
    // ---- worker ----
    const short8* bpr = (const short8*)(ws + O_BPR) + (long)rank * 80 * 64;
#pragma unroll
    for (int i = 0; i < 16; ++i) bq[i * 256 + tid] = bpr[16 * 64 + i * 256 + tid];
    short8 w0a[8], w0b[8];
#pragma unroll
    for (int ks = 0; ks < 8; ++ks) { w0a[ks] = bpr[ks * 64 + l]; w0b[ks] = bpr[(8 + ks) * 64 + l]; }
    u16* hbuf = (u16*)(ws + O_H);
    float* csave = (float*)(ws + O_C);
    const u16* axc = (const u16*)(ws + O_AX) + (long)(chunk & 1) * axstride;
    int n16 = l & 15, kg = l >> 4;
    int hu = rank * 8 + (n16 & 7);
    bool own = n16 < 8;
    float c0[4], c1[4], c2[4];
#pragma unroll
    for (int i = 0; i < 4; ++i) {
        int row = w * 16 + kg * 4 + i;
        if (first || !own) { c0[i] = 0.f; c1[i] = 0.f; c2[i] = 0.f; }
        else {
            c0[i] = csave[(0 * 64 + row) * 256 + hu];
            c1[i] = csave[(1 * 64 + row) * 256 + hu];
            c2[i] = csave[(2 * 64 + row) * 256 + hu];
        }
    }
    __syncthreads();
    u32 lph = 0;
    int arow = (w * 16 + n16) * 256 + kg * 8;
    const int sEnd = t0 + tc + 2;
    for (int s = t0; s < sEnd; ++s) {
        int par = s & 1, prv = par ^ 1;
        const u16* h0p = hbuf + (0 * 2 + prv) * 16384; u16* h0c = hbuf + (0 * 2 + par) * 16384;
        const u16* h1p = hbuf + (1 * 2 + prv) * 16384; u16* h1c = hbuf + (1 * 2 + par) * 16384;
        const u16* h2p = hbuf + (2 * 2 + prv) * 16384; u16* h2c = hbuf + (2 * 2 + par) * 16384;
        bool d0 = s < t0 + tc, d1 = s > t0 && s <= t0 + tc, d2 = s > t0 + 1;
        // ---- prefetch Ax for all active stages (h-independent) ----
        float px0[2][4], px1[2][4], px2[2][4];
        if (d0) loadax(px0, axc + (long)(s - t0) * 196608 + (long)rank * 2048, n16, w, kg);
        if (d1) loadax(px1, axc + (long)(s - 1 - t0) * 196608 + (long)(32 + rank) * 2048, n16, w, kg);
        if (d2) loadax(px2, axc + (long)(s - 2 - t0) * 196608 + (long)(64 + rank) * 2048, n16, w, kg);
        // S0 at t=s : reads h0(s-1) [prv]
        if (d0) {
            f32x4 a0 = {0.f, 0.f, 0.f, 0.f}, a1 = {0.f, 0.f, 0.f, 0.f};
#pragma unroll
            for (int ks = 0; ks < 8; ++ks) {
                short8 a = *(const short8*)(h0p + arow + ks * 32);
                a0 = mfma16(a, w0a[ks], a0); a1 = mfma16(a, w0b[ks], a1);
            }
            gate_update(a0, a1, px0[0], px0[1], c0, h0c, w, l, hu);
        }
        // S1 at t=s-1 : reads h0(s-1) [prv], h1(s-2) [prv]
        if (d1) {
            f32x4 a0 = {0.f, 0.f, 0.f, 0.f}, a1 = {0.f, 0.f, 0.f, 0.f};
            acc8(h0p, arow, bq, 0, 16, l, a0, a1);
            acc8(h1p, arow, bq, 8, 24, l, a0, a1);
            gate_update(a0, a1, px1[0], px1[1], c1, h1c, w, l, hu);
        }
        // S2 at t=s-2 : reads h1(s-2) [prv], h2(s-3) [prv]
        if (d2) {
            f32x4 a0 = {0.f, 0.f, 0.f, 0.f}, a1 = {0.f, 0.f, 0.f, 0.f};
            acc8(h1p, arow, bq, 32, 48, l, a0, a1);
            acc8(h2p, arow, bq, 40, 56, l, a0, a1);
            gate_update(a0, a1, px2[0], px2[1], c2, h2c, w, l, hu);
        }
        if (s + 1 < sEnd) {
            ++lph;
            barrier_step(slot, rank, lph, tid, l, w);
        }
    }
    if (own) {
#pragma unroll
        for (int i = 0; i < 4; ++i) {
            int row = w * 16 + kg * 4 + i;
            csave[(0 * 64 + row) * 256 + hu] = c0[i];
            csave[(1 * 64 + row) * 256 + hu] = c1[i];
            csave[(2 * 64 + row) * 256 + hu] = c2[i];
        }
        if (last) {
            int f0 = (TSEQ - 1) & 1, f1 = TSEQ & 1, f2 = (TSEQ + 1) & 1;
#pragma unroll
            for (int i = 0; i < 4; ++i) {
                int row = w * 16 + kg * 4 + i;
                float h0v = b2f(hbuf[(0 * 2 + f0) * 16384 + row * 256 + hu]);
                float h1v = b2f(hbuf[(1 * 2 + f1) * 16384 + row * 256 + hu]);
                float h2v = b2f(hbuf[(2 * 2 + f2) * 16384 + row * 256 + hu]);
                if (isbf) {
                    u16* o = (u16*)outv;
                    o[row * 1536 + 0 + hu] = f2b(c0[i]);
                    o[row * 1536 + 256 + hu] = f2b(h0v);
                    o[row * 1536 + 512 + hu] = f2b(c1[i]);
                    o[row * 1536 + 768 + hu] = f2b(h1v);
                    o[row * 1536 + 1024 + hu] = f2b(c2[i]);
                    o[row * 1536 + 1280 + hu] = f2b(h2v);
                } else {
                    float* o = (float*)outv;
                    o[row * 1536 + 0 + hu] = c0[i];
                    o[row * 1536 + 256 + hu] = h0v;
                    o[row * 1536 + 512 + hu] = c1[i];
                    o[row * 1536 + 768 + hu] = h1v;
                    o[row * 1536 + 1024 + hu] = c2[i];
                    o[row * 1536 + 1280 + hu] = h2v;
                }
            }
        }
    }
}

extern "C" void kernel_launch(void* const* d_in, const int* in_sizes, int n_in,
                              void* d_out, int out_size, void* d_ws, size_t ws_size,
                              hipStream_t stream) {
    const int* ids = (const int*)d_in[0];
    const void* emb = d_in[1];
    const void* W0x = d_in[2]; const void* W0h = d_in[3]; const void* b0 = d_in[4];
    const void* W1x = d_in[5]; const void* W1h = d_in[6]; const void* b1 = d_in[7];
    const void* W2x = d_in[8]; const void* W2h = d_in[9]; const void* b2 = d_in[10];
    char* ws = (char*)d_ws;

    long avail = (long)ws_size - O_AX;
    long per_t = 64L * 3072 * 2;
    int tc_max = (int)(avail / (2 * per_t));   // double-buffered Ax
    if (tc_max > TSEQ) tc_max = TSEQ;
    if (tc_max < 4) tc_max = 4;                // keep nck <= 250 (slots: 256)
    long axstride = (long)tc_max * 196608;
    int nck = (TSEQ + tc_max - 1) / tc_max;

    hipMemsetAsync(ws + O_SYNC, 0, 1572864, stream);
    hipMemsetAsync(ws + O_H, 0, 196608, stream);
    k_detect<<<1, 256, 0, stream>>>((const u32*)emb, (int*)(ws + O_FLAG));
    k_pack_a<<<384, 256, 0, stream>>>(W0x, W1x, W2x, d_ws);
    k_pack_r<<<640, 256, 0, stream>>>(W0h, W1x, W1h, W2x, W2h, d_ws);

    int tc0 = (TSEQ < tc_max) ? TSEQ : tc_max;
    { dim3 g(12, (unsigned)tc0);
      k_gemm_x<<<g, 256, 0, stream>>>(ids, emb, b0, b1, b2, d_ws, 0); }

    for (int c = 0; c < nck; ++c) {
        int t0 = c * tc_max;
        int tc = TSEQ - t0; if (tc > tc_max) tc = tc_max;
        int t0n = t0 + tc;
        int tcn = 0;
        if (c + 1 < nck) { tcn = TSEQ - t0n; if (tcn > tc_max) tcn = tc_max; }
        k_rec<<<GRID_REC, 256, 0, stream>>>(ids, emb, b0, b1, b2, d_ws, d_out,
                                            c, t0, tc, t0n, tcn, axstride,
                                            c == 0, t0 + tc == TSEQ);
    }
}

// Round 6
// 9895.050 us; speedup vs baseline: 2.1566x; 1.0056x over previous
//
#include <hip/hip_runtime.h>
#include <hip/hip_bf16.h>

// DeepLSTM on MI355X — R6: remove HBM from the recurrent critical path.
//   R5 post-mortem: barrier protocol changes (R2/R4/R5) all landed ~10us/step ->
//   bottleneck is the per-step cold Ax fetch (12KB/block from HBM/MALL) whose tail
//   latency is maxed over 32 blocks by the barrier, plus helper HBM-write interference.
//   R6: (1) distance-1 register prefetch of Ax slices (consume px loaded last superstep);
//       (2) single-dispatch mode when ws fits 1000 steps: ALL Ax precomputed by a
//           full-GPU k_gemm_x before k_rec -> no helper traffic during recurrence;
//       (3) R5 barrier unchanged.
// Superstep s computes S0(t=s), S1(t=s-1), S2(t=s-2); reads parity s^1, writes parity s.

typedef __attribute__((ext_vector_type(8))) short short8;
typedef __attribute__((ext_vector_type(4))) float f32x4;
typedef unsigned short u16;
typedef unsigned int u32;

#define TSEQ 1000
#define NBLK 32
#define GRID_REC 256
#define NHELP (GRID_REC - NBLK)

// ws layout (bytes). Sync slot (per chunk, stride 6144): election @+0,
// L2 flags @+1024 (32 x 64B), atomic fallback flags @+3072 (32 x 64B).
#define O_FLAG 0L
#define O_SYNC 512L
#define O_H    1573376L  // h[3][2][64][256] bf16 = 196608
#define O_C    1769984L  // c_save[3][64][256] f32 = 196608
#define O_BPA  1966592L  // packed phase-A B: 192 tiles * 8 ks * 64 lanes * 16B
#define O_BPR  3539456L  // packed rec B: 32 rank * 80 fb * 64 lanes * 16B
#define O_AX   6160896L  // Ax: single buffer (1000 t) or 2 chunked buffers ([t][3][32][64*32])

__device__ __forceinline__ u16 f2b(float v) {
    __hip_bfloat16 h = __float2bfloat16(v);
    u16 u; __builtin_memcpy(&u, &h, 2); return u;
}
__device__ __forceinline__ float b2f(u16 u) {
    __hip_bfloat16 h; __builtin_memcpy(&h, &u, 2); return __bfloat162float(h);
}
__device__ __forceinline__ float rdw(const void* p, long i, int isbf) {
    return isbf ? b2f(((const u16*)p)[i]) : ((const float*)p)[i];
}
__device__ __forceinline__ float sigm(float x) { return 1.0f / (1.0f + __expf(-x)); }
__device__ __forceinline__ float tanh_(float x) { return 1.0f - 2.0f / (1.0f + __expf(2.0f * x)); }
__device__ __forceinline__ f32x4 mfma16(short8 a, short8 b, f32x4 c) {
    return __builtin_amdgcn_mfma_f32_16x16x32_bf16(a, b, c, 0, 0, 0);
}

// ---------- dtype detect ----------
__global__ void k_detect(const u32* __restrict__ embw, int* flag) {
    __shared__ int cnt[256];
    int tid = threadIdx.x, c = 0;
    for (int i = 0; i < 16; ++i) {
        u32 w = embw[tid * 16 + i];
        u32 e = (w >> 7) & 0xFF;
        c += (e >= 110 && e <= 126) ? 1 : 0;
    }
    cnt[tid] = c; __syncthreads();
    for (int s = 128; s > 0; s >>= 1) { if (tid < s) cnt[tid] += cnt[tid + s]; __syncthreads(); }
    if (tid == 0) flag[0] = (cnt[0] > 2048) ? 1 : 0;
}

// ---------- pack phase-A B ----------
__global__ void k_pack_a(const void* W0x, const void* W1x, const void* W2x, void* wsv) {
    char* ws = (char*)wsv;
    int isbf = *(const int*)(ws + O_FLAG);
    int l = threadIdx.x & 63, w = threadIdx.x >> 6;
    int gid = blockIdx.x * 4 + w;          // 0..1535 = tile*8 + ks
    int tile = gid >> 3, ks = gid & 7;
    int L = tile >> 6, wi = tile & 63, bk = wi >> 1, half = wi & 1;
    int n16 = l & 15, g = half * 2 + (n16 >> 3), u = n16 & 7;
    int n = g * 256 + bk * 8 + u;
    const void* W = (L == 0) ? W0x : ((L == 1) ? W1x : W2x);
    union { u16 us[8]; short8 v; } tmp;
#pragma unroll
    for (int j = 0; j < 8; ++j) {
        int k = ks * 32 + (l >> 4) * 8 + j;
        tmp.us[j] = f2b(rdw(W, (long)k * 1024 + n, isbf));
    }
    ((short8*)(ws + O_BPA))[(long)(tile * 8 + ks) * 64 + l] = tmp.v;
}

// ---------- pack recurrent B ----------
__global__ void k_pack_r(const void* W0h, const void* W1x, const void* W1h,
                         const void* W2x, const void* W2h, void* wsv) {
    char* ws = (char*)wsv;
    int isbf = *(const int*)(ws + O_FLAG);
    int l = threadIdx.x & 63, w = threadIdx.x >> 6;
    int gid = blockIdx.x * 4 + w;          // 0..2559 = rank*80 + fb
    int bk = gid / 80, fb = gid % 80;
    int s, nt, ks;
    if (fb < 16) { s = 0; nt = fb >> 3; ks = fb & 7; }
    else if (fb < 48) { s = 1; int f = fb - 16; nt = f >> 4; ks = f & 15; }
    else { s = 2; int f = fb - 48; nt = f >> 4; ks = f & 15; }
    int n16 = l & 15, g = nt * 2 + (n16 >> 3), u = n16 & 7;
    int n = g * 256 + bk * 8 + u;
    union { u16 us[8]; short8 v; } tmp;
#pragma unroll
    for (int j = 0; j < 8; ++j) {
        int k = ks * 32 + (l >> 4) * 8 + j;
        float v;
        if (s == 0) v = rdw(W0h, (long)k * 1024 + n, isbf);
        else if (s == 1) v = (k < 256) ? rdw(W1x, (long)(256 + k) * 1024 + n, isbf)
                                       : rdw(W1h, (long)(k - 256) * 1024 + n, isbf);
        else v = (k < 256) ? rdw(W2x, (long)(256 + k) * 1024 + n, isbf)
                           : rdw(W2h, (long)(k - 256) * 1024 + n, isbf);
        tmp.us[j] = f2b(v);
    }
    ((short8*)(ws + O_BPR))[(long)bk * 80 * 64 + (long)fb * 64 + l] = tmp.v;
}

// ---------- x-GEMM tile: 64 batch rows x 256 gate cols at timestep t ----------
// Output layout (per t): [L(3)][rank(32)][row(64)*32 + half*16 + n16]  (4KB blocks)
__device__ __forceinline__ void gemm_tile(const int* __restrict__ ids, const void* __restrict__ emb,
    const void* b0, const void* b1, const void* b2, const short8* __restrict__ bpa,
    int isbf, int seg, int t, u16* __restrict__ axp) {
    int tid = threadIdx.x, l = tid & 63, w = tid >> 6;
    int n16 = l & 15, kg = l >> 4;
    short8 a[4][8];
#pragma unroll
    for (int mt = 0; mt < 4; ++mt) {
        int b = mt * 16 + n16;
        long id = ids[b * TSEQ + t];
        if (isbf) {
            const u16* ep = (const u16*)emb + id * 256;
#pragma unroll
            for (int ks = 0; ks < 8; ++ks)
                a[mt][ks] = *(const short8*)(ep + ks * 32 + kg * 8);
        } else {
            const float* ep = (const float*)emb + id * 256;
#pragma unroll
            for (int ks = 0; ks < 8; ++ks) {
                f32x4 v0 = *(const f32x4*)(ep + ks * 32 + kg * 8);
                f32x4 v1 = *(const f32x4*)(ep + ks * 32 + kg * 8 + 4);
                union { u16 us[8]; short8 v; } tmp;
#pragma unroll
                for (int j = 0; j < 4; ++j) { tmp.us[j] = f2b(v0[j]); tmp.us[4 + j] = f2b(v1[j]); }
                a[mt][ks] = tmp.v;
            }
        }
    }
#pragma unroll
    for (int nt = 0; nt < 4; ++nt) {
        int tile = seg * 16 + w * 4 + nt;
        f32x4 acc[4];
#pragma unroll
        for (int mt = 0; mt < 4; ++mt) acc[mt] = (f32x4){0.f, 0.f, 0.f, 0.f};
#pragma unroll
        for (int ks = 0; ks < 8; ++ks) {
            short8 bb = bpa[(long)(tile * 8 + ks) * 64 + l];
#pragma unroll
            for (int mt = 0; mt < 4; ++mt) acc[mt] = mfma16(a[mt][ks], bb, acc[mt]);
        }
        int L = tile >> 6, wi = tile & 63, bkk = wi >> 1, half = wi & 1;
        int g = half * 2 + (n16 >> 3), u = n16 & 7;
        const void* bias = (L == 0) ? b0 : ((L == 1) ? b1 : b2);
        float bv = rdw(bias, g * 256 + bkk * 8 + u, isbf);
        long base = (long)(L * 32 + bkk) * 2048 + half * 16 + n16;
#pragma unroll
        for (int mt = 0; mt < 4; ++mt)
#pragma unroll
            for (int i = 0; i < 4; ++i) {
                int row = mt * 16 + kg * 4 + i;
                axp[base + (long)row * 32] = f2b(acc[mt][i] + bv);
            }
    }
}

__global__ __launch_bounds__(256, 1) void k_gemm_x(
    const int* __restrict__ ids, const void* __restrict__ emb,
    const void* b0, const void* b1, const void* b2, void* wsv, int t0) {
    char* ws = (char*)wsv;
    int isbf = *(const int*)(ws + O_FLAG);
    const short8* bpa = (const short8*)(ws + O_BPA);
    u16* ax = (u16*)(ws + O_AX);   // buffer 0
    gemm_tile(ids, emb, b0, b1, b2, bpa, isbf, blockIdx.x, t0 + blockIdx.y,
              ax + (long)blockIdx.y * 196608);
}

// ---------- superstep barrier: L2-local poll + agent-atomic fallback ----------
__device__ __forceinline__ void barrier_step(char* slot, int rank, u32 p, int tid, int l, int w) {
    volatile u32* fl2 = (volatile u32*)(slot + 1024);
    u32* fat = (u32*)(slot + 3072);
    __syncthreads();            // drains each wave's vmcnt before s_barrier -> h stores in L2
    if (tid == 0) {
        fl2[rank * 16] = p;
        __hip_atomic_store(fat + rank * 16, p, __ATOMIC_RELAXED, __HIP_MEMORY_SCOPE_AGENT);
    }
    if (w == 0) {
        int idx = l & 31;
        volatile u32* myl2 = fl2 + idx * 16;
        u32* myat = fat + idx * 16;
        for (int it = 0; it < (1 << 20); ++it) {
            asm volatile("buffer_inv" ::: "memory");
            u32 v = *myl2;
            if (__all((int)(v >= p))) break;
            if ((it & 15) == 15) {
                u32 va = __hip_atomic_load(myat, __ATOMIC_RELAXED, __HIP_MEMORY_SCOPE_AGENT);
                if (__all((int)(va >= p))) break;
            }
            __builtin_amdgcn_s_sleep(1);
        }
    }
    __syncthreads();
    asm volatile("buffer_inv" ::: "memory");   // acquire: L1 invalidate before h reads
}

__device__ __forceinline__ void gate_update(f32x4 acc0, f32x4 acc1,
    const float* ax0, const float* ax1, float* cst, u16* hOut, int w, int l, int hu) {
    int n16 = l & 15, kg = l >> 4;
    bool own = n16 < 8;
#pragma unroll
    for (int i = 0; i < 4; ++i) {
        float g0 = acc0[i] + ax0[i];   // own: i-gate | partner: j-gate
        float g1 = acc1[i] + ax1[i];   // own: f-gate | partner: o-gate
        float pj = __shfl_xor(g0, 8, 64);
        float po = __shfl_xor(g1, 8, 64);
        float cn = sigm(g1) * cst[i] + sigm(g0) * tanh_(pj);
        float hn = sigm(po) * tanh_(cn);
        cst[i] = own ? cn : 0.0f;
        if (own) {
            int row = w * 16 + kg * 4 + i;
            hOut[row * 256 + hu] = f2b(hn);
        }
    }
}

// load one stage's Ax slice into registers (h-independent)
__device__ __forceinline__ void loadax(float dst[2][4], const u16* axs, int n16, int w, int kg) {
#pragma unroll
    for (int i = 0; i < 4; ++i) {
        int row = w * 16 + kg * 4 + i;
        dst[0][i] = b2f(axs[row * 32 + n16]);
        dst[1][i] = b2f(axs[row * 32 + 16 + n16]);
    }
}

__device__ __forceinline__ void acc8(const u16* h, int arow, const short8* bq,
    int i0, int i1, int l, f32x4& a0, f32x4& a1) {
#pragma unroll
    for (int ks = 0; ks < 8; ++ks) {
        short8 a = *(const short8*)(h + arow + ks * 32);
        a0 = mfma16(a, bq[(i0 + ks) * 64 + l], a0);
        a1 = mfma16(a, bq[(i1 + ks) * 64 + l], a1);
    }
}

__global__ __launch_bounds__(256, 1) void k_rec(
    const int* __restrict__ ids, const void* __restrict__ emb,
    const void* b0, const void* b1, const void* b2,
    void* wsv, void* outv, int chunk, int t0, int tc, int t0n, int tcn,
    long axstride, int first, int last) {
    __shared__ short8 bq[4096];
    __shared__ int sh_role, sh_rank;
    char* ws = (char*)wsv;
    int tid = threadIdx.x, l = tid & 63, w = tid >> 6;
    int isbf = *(const int*)(ws + O_FLAG);
    char* slot = ws + O_SYNC + (long)chunk * 6144;
    int* syn = (int*)slot;
    // ---- census & election (once per dispatch; agent atomics OK here) ----
    if (tid == 0) {
        int xcc;
        asm volatile("s_getreg_b32 %0, hwreg(HW_REG_XCC_ID, 0, 8)" : "=s"(xcc));
        xcc &= 7;
        int r = __hip_atomic_fetch_add(syn + 2 + xcc, 1, __ATOMIC_RELAXED, __HIP_MEMORY_SCOPE_AGENT);
        int role = 1, rank = -1;
        if (r < NBLK) {
            if (r == NBLK - 1) {
                int exp = 0;
                __hip_atomic_compare_exchange_strong(syn + 10, &exp, xcc + 1,
                    __ATOMIC_RELAXED, __ATOMIC_RELAXED, __HIP_MEMORY_SCOPE_AGENT);
            }
            int wv;
            while ((wv = __hip_atomic_load(syn + 10, __ATOMIC_RELAXED, __HIP_MEMORY_SCOPE_AGENT)) == 0)
                __builtin_amdgcn_s_sleep(8);
            if (wv == xcc + 1) { role = 0; rank = r; }
        }
        if (role) rank = __hip_atomic_fetch_add(syn + 11, 1, __ATOMIC_RELAXED, __HIP_MEMORY_SCOPE_AGENT);
        sh_role = role; sh_rank = rank;
    }
    __syncthreads();
    int role = sh_role, rank = sh_rank;

    if (role) {   // ---- helper: next chunk's x-GEMM (chunked fallback mode only) ----
        asm volatile("s_setprio 0");
        if (tcn > 0) {
            const short8* bpa = (const short8*)(ws + O_BPA);
            u16* axn = (u16*)(ws + O_AX) + (long)((chunk + 1) & 1) * axstride;
            for (int job = rank; job < 12 * tcn; job += NHELP) {
                int seg = job % 12, tl = job / 12;
                gemm_tile(ids, emb, b0, b1, b2, bpa, isbf, seg, t0n + tl,
                          axn + (long)tl * 196608);
            }
        }
        return;
    }
    asm volatile("s_setprio 3");
    // ---- worker ----
    const short8* bpr = (const short8*)(ws + O_BPR) + (long)rank * 80 * 64;
#pragma unroll
    for (int i = 0; i < 16; ++i) bq[i * 256 + tid] = bpr[16 * 64 + i * 256 + tid];
    short8 w0a[8], w0b[8];
#pragma unroll
    for (int ks = 0; ks < 8; ++ks) { w0a[ks] = bpr[ks * 64 + l]; w0b[ks] = bpr[(8 + ks) * 64 + l]; }
    u16* hbuf = (u16*)(ws + O_H);
    float* csave = (float*)(ws + O_C);
    const u16* axc = (const u16*)(ws + O_AX) + (long)(chunk & 1) * axstride;
    int n16 = l & 15, kg = l >> 4;
    int hu = rank * 8 + (n16 & 7);
    bool own = n16 < 8;
    float c0[4], c1[4], c2[4];
#pragma unroll
    for (int i = 0; i < 4; ++i) {
        int row = w * 16 + kg * 4 + i;
        if (first || !own) { c0[i] = 0.f; c1[i] = 0.f; c2[i] = 0.f; }
        else {
            c0[i] = csave[(0 * 64 + row) * 256 + hu];
            c1[i] = csave[(1 * 64 + row) * 256 + hu];
            c2[i] = csave[(2 * 64 + row) * 256 + hu];
        }
    }
    __syncthreads();
    u32 lph = 0;
    int arow = (w * 16 + n16) * 256 + kg * 8;
    const int sEnd = t0 + tc + 2;
    const int tEnd = t0 + tc;
    // ---- distance-1 pipelined Ax prefetch: pxA/pxB ping-pong ----
    float pxA[3][2][4], pxB[3][2][4];
    if (tc > 0) loadax(pxA[0], axc + (long)rank * 2048, n16, w, kg);   // s=t0: only S0 active

#define SSTEP(CUR, NXT, S)                                                                         \
    do {                                                                                           \
        int par = (S) & 1, prv = par ^ 1;                                                          \
        const u16* h0p = hbuf + (0 * 2 + prv) * 16384; u16* h0c = hbuf + (0 * 2 + par) * 16384;    \
        const u16* h1p = hbuf + (1 * 2 + prv) * 16384; u16* h1c = hbuf + (1 * 2 + par) * 16384;    \
        const u16* h2p = hbuf + (2 * 2 + prv) * 16384; u16* h2c = hbuf + (2 * 2 + par) * 16384;    \
        int q = (S) + 1;                                                                           \
        if (q < sEnd) {                                                                            \
            if (q < tEnd)                                                                          \
                loadax(NXT[0], axc + (long)(q - t0) * 196608 + (long)rank * 2048, n16, w, kg);     \
            if (q > t0 && q <= tEnd)                                                               \
                loadax(NXT[1], axc + (long)(q - 1 - t0) * 196608 + (long)(32 + rank) * 2048, n16, w, kg); \
            if (q > t0 + 1)                                                                        \
                loadax(NXT[2], axc + (long)(q - 2 - t0) * 196608 + (long)(64 + rank) * 2048, n16, w, kg); \
        }                                                                                          \
        if ((S) < tEnd) {                                                                          \
            f32x4 a0 = {0.f, 0.f, 0.f, 0.f}, a1 = {0.f, 0.f, 0.f, 0.f};                            \
            _Pragma("unroll")                                                                      \
            for (int ks = 0; ks < 8; ++ks) {                                                       \
                short8 a = *(const short8*)(h0p + arow + ks * 32);                                 \
                a0 = mfma16(a, w0a[ks], a0); a1 = mfma16(a, w0b[ks], a1);                          \
            }                                                                                      \
            gate_update(a0, a1, CUR[0][0], CUR[0][1], c0, h0c, w, l, hu);                          \
        }                                                                                          \
        if ((S) > t0 && (S) <= tEnd) {                                                             \
            f32x4 a0 = {0.f, 0.f, 0.f, 0.f}, a1 = {0.f, 0.f, 0.f, 0.f};                            \
            acc8(h0p, arow, bq, 0, 16, l, a0, a1);                                                 \
            acc8(h1p, arow, bq, 8, 24, l, a0, a1);                                                 \
            gate_update(a0, a1, CUR[1][0], CUR[1][1], c1, h1c, w, l, hu);                          \
        }                                                                                          \
        if ((S) > t0 + 1) {                                                                        \
            f32x4 a0 = {0.f, 0.f, 0.f, 0.f}, a1 = {0.f, 0.f, 0.f, 0.f};                            \
            acc8(h1p, arow, bq, 32, 48, l, a0, a1);                                                \
            acc8(h2p, arow, bq, 40, 56, l, a0, a1);                                                \
            gate_update(a0, a1, CUR[2][0], CUR[2][1], c2, h2c, w, l, hu);                          \
        }                                                                                          \
        if ((S) + 1 < sEnd) { ++lph; barrier_step(slot, rank, lph, tid, l, w); }                   \
    } while (0)

    for (int s = t0; s < sEnd; ) {
        SSTEP(pxA, pxB, s); ++s; if (s >= sEnd) break;
        SSTEP(pxB, pxA, s); ++s;
    }
#undef SSTEP

    if (own) {
#pragma unroll
        for (int i = 0; i < 4; ++i) {
            int row = w * 16 + kg * 4 + i;
            csave[(0 * 64 + row) * 256 + hu] = c0[i];
            csave[(1 * 64 + row) * 256 + hu] = c1[i];
            csave[(2 * 64 + row) * 256 + hu] = c2[i];
        }
        if (last) {
            int f0 = (TSEQ - 1) & 1, f1 = TSEQ & 1, f2 = (TSEQ + 1) & 1;
#pragma unroll
            for (int i = 0; i < 4; ++i) {
                int row = w * 16 + kg * 4 + i;
                float h0v = b2f(hbuf[(0 * 2 + f0) * 16384 + row * 256 + hu]);
                float h1v = b2f(hbuf[(1 * 2 + f1) * 16384 + row * 256 + hu]);
                float h2v = b2f(hbuf[(2 * 2 + f2) * 16384 + row * 256 + hu]);
                if (isbf) {
                    u16* o = (u16*)outv;
                    o[row * 1536 + 0 + hu] = f2b(c0[i]);
                    o[row * 1536 + 256 + hu] = f2b(h0v);
                    o[row * 1536 + 512 + hu] = f2b(c1[i]);
                    o[row * 1536 + 768 + hu] = f2b(h1v);
                    o[row * 1536 + 1024 + hu] = f2b(c2[i]);
                    o[row * 1536 + 1280 + hu] = f2b(h2v);
                } else {
                    float* o = (float*)outv;
                    o[row * 1536 + 0 + hu] = c0[i];
                    o[row * 1536 + 256 + hu] = h0v;
                    o[row * 1536 + 512 + hu] = c1[i];
                    o[row * 1536 + 768 + hu] = h1v;
                    o[row * 1536 + 1024 + hu] = c2[i];
                    o[row * 1536 + 1280 + hu] = h2v;
                }
            }
        }
    }
}

extern "C" void kernel_launch(void* const* d_in, const int* in_sizes, int n_in,
                              void* d_out, int out_size, void* d_ws, size_t ws_size,
                              hipStream_t stream) {
    const int* ids = (const int*)d_in[0];
    const void* emb = d_in[1];
    const void* W0x = d_in[2]; const void* W0h = d_in[3]; const void* b0 = d_in[4];
    const void* W1x = d_in[5]; const void* W1h = d_in[6]; const void* b1 = d_in[7];
    const void* W2x = d_in[8]; const void* W2h = d_in[9]; const void* b2 = d_in[10];
    char* ws = (char*)d_ws;

    long avail = (long)ws_size - O_AX;
    long per_t = 64L * 3072 * 2;
    int tc_single = (int)(avail / per_t);

    hipMemsetAsync(ws + O_SYNC, 0, 1572864, stream);
    hipMemsetAsync(ws + O_H, 0, 196608, stream);
    k_detect<<<1, 256, 0, stream>>>((const u32*)emb, (int*)(ws + O_FLAG));
    k_pack_a<<<384, 256, 0, stream>>>(W0x, W1x, W2x, d_ws);
    k_pack_r<<<640, 256, 0, stream>>>(W0h, W1x, W1h, W2x, W2h, d_ws);

    if (tc_single >= TSEQ) {
        // ---- single-dispatch mode: all Ax precomputed; no helper traffic during k_rec ----
        dim3 g(12, TSEQ);
        k_gemm_x<<<g, 256, 0, stream>>>(ids, emb, b0, b1, b2, d_ws, 0);
        k_rec<<<GRID_REC, 256, 0, stream>>>(ids, emb, b0, b1, b2, d_ws, d_out,
                                            0, 0, TSEQ, 0, 0, 0L, 1, 1);
        return;
    }

    // ---- chunked fallback (double-buffered Ax, helpers compute next chunk) ----
    int tc_max = (int)(avail / (2 * per_t));
    if (tc_max > TSEQ) tc_max = TSEQ;
    if (tc_max < 4) tc_max = 4;
    long axstride = (long)tc_max * 196608;
    int nck = (TSEQ + tc_max - 1) / tc_max;

    int tc0 = (TSEQ < tc_max) ? TSEQ : tc_max;
    { dim3 g(12, (unsigned)tc0);
      k_gemm_x<<<g, 256, 0, stream>>>(ids, emb, b0, b1, b2, d_ws, 0); }

    for (int c = 0; c < nck; ++c) {
        int t0 = c * tc_max;
        int tc = TSEQ - t0; if (tc > tc_max) tc = tc_max;
        int t0n = t0 + tc;
        int tcn = 0;
        if (c + 1 < nck) { tcn = TSEQ - t0n; if (tcn > tc_max) tcn = tc_max; }
        k_rec<<<GRID_REC, 256, 0, stream>>>(ids, emb, b0, b1, b2, d_ws, d_out,
                                            c, t0, tc, t0n, tcn, axstride,
                                            c == 0, t0 + tc == TSEQ);
    }
}